// Round 15
// baseline (6953.282 us; speedup 1.0000x reference)
//
#include <hip/hip_runtime.h>
#include <math.h>

#define VOCAB 32000
#define D_IN  256
#define D_H   32
#define B_SZ  16
#define S_LEN 512
#define NTOK  (B_SZ * S_LEN)   // 8192

#define NWIN  256              // 32-token windows (16 chunks x 16 batches)
#define NV1   16               // sum vocab splits
#define VT1   (VOCAB / 16 / NV1)   // 125
#define NVO   8                // out vocab splits
#define VTO   (VOCAB / 16 / NVO)   // 250
#define NSB   224
#define NOB   224
#define GRID_F (1 + NSB + NOB) // 449

typedef __bf16 bf16;
typedef __attribute__((ext_vector_type(8))) __bf16 bf16x8;
typedef __attribute__((ext_vector_type(4))) __bf16 bf16x4;
typedef __attribute__((ext_vector_type(4))) float f32x4;

__device__ __forceinline__ float sigf(float x) {
    return 1.0f / (1.0f + __expf(-x));
}

__device__ __forceinline__ float tanhfast(float x) {
    float ax = fabsf(x);
    float e = __expf(-2.0f * ax);
    float r = (1.0f - e) / (1.0f + e);
    return copysignf(r, x);
}

__device__ __forceinline__ float dot4(float4 a, float4 b) {
    return a.x * b.x + a.y * b.y + a.z * b.z + a.w * b.w;
}

// ---------------------------------------------------------------------------
__global__ __launch_bounds__(256) void k_cvt_w(
    const float* __restrict__ W, bf16* __restrict__ Whi, bf16* __restrict__ Wlo)
{
    const long i = ((long)blockIdx.x * 256 + threadIdx.x) * 4;
    float4 w = *(const float4*)(W + i);
    bf16 h0 = (bf16)w.x, h1 = (bf16)w.y, h2 = (bf16)w.z, h3 = (bf16)w.w;
    bf16 l0 = (bf16)(w.x - (float)h0), l1 = (bf16)(w.y - (float)h1);
    bf16 l2 = (bf16)(w.z - (float)h2), l3 = (bf16)(w.w - (float)h3);
    bf16x4 hv = {h0, h1, h2, h3}, lv = {l0, l1, l2, l3};
    *(bf16x4*)(Whi + i) = hv;
    *(bf16x4*)(Wlo + i) = lv;
}

__global__ __launch_bounds__(256) void k_zero(int* __restrict__ flags)
{
    for (int i = threadIdx.x; i < 544; i += 256) flags[i] = 0;
}

// ---------------------------------------------------------------------------
// Kernel A: input gates packed into the LSTM's D/C-fragment order (v2):
// float index (((s*8 + w)*64 + lane)*4 + gt), lane = lq*16 + b,
// holds G1[b][s][g = gt*32 + 4w + lq].
// ---------------------------------------------------------------------------
__global__ __launch_bounds__(128) void k_embed_gates(
    const int* __restrict__ x_ids, const float* __restrict__ emb,
    const float* __restrict__ W_ih1, const float* __restrict__ b_ih1,
    const float* __restrict__ b_hh1, float* __restrict__ G1d)
{
    __shared__ float4 xs[4][64];
    const int tid = threadIdx.x;
    const int t0  = blockIdx.x * 4;
    const int r0  = tid >> 6, j = tid & 63;
    #pragma unroll
    for (int rr = 0; rr < 2; ++rr) {
        int r = rr * 2 + r0;
        long id = x_ids[t0 + r];
        xs[r][j] = ((const float4*)(emb + id * (long)D_IN))[j];
    }
    __syncthreads();

    const int g = tid;
    const float4* wrow = (const float4*)(W_ih1 + (long)g * D_IN);
    const float bias = b_ih1[g] + b_hh1[g];
    float a0 = bias, a1 = bias, a2 = bias, a3 = bias;
    #pragma unroll 8
    for (int jj = 0; jj < 64; ++jj) {
        float4 w = wrow[jj];
        a0 += dot4(w, xs[0][jj]);
        a1 += dot4(w, xs[1][jj]);
        a2 += dot4(w, xs[2][jj]);
        a3 += dot4(w, xs[3][jj]);
    }
    const int b  = t0 >> 9;
    const int s0 = t0 & 511;
    const int gt = g >> 5;
    const int u  = g & 31;
    const int w  = u >> 2;
    const int lq = u & 3;
    const int lane = lq * 16 + b;
    float vals[4] = {a0, a1, a2, a3};
    #pragma unroll
    for (int k = 0; k < 4; ++k) {
        G1d[(((long)(s0 + k) * 8 + w) * 64 + lane) * 4 + gt] = vals[k];
    }
}

// ---------------------------------------------------------------------------
// Fused kernel: block 0 = MFMA LSTM (LDS ring, 16-step flush, prog publish);
// blocks 1..NSB = fc_sum (+inv); rest = fc_out.
// Capacity: launch_bounds(512,4) -> <=128 VGPR -> 2 blk/CU; LDS 76KB -> 2/CU;
// grid 449 <= 512 -> all co-resident, spin-waits safe.
// ---------------------------------------------------------------------------
__global__ __launch_bounds__(512, 4) void k_fused(
    const float* __restrict__ G1d,
    const float* __restrict__ W_hh1,
    const float* __restrict__ W_ih2, const float* __restrict__ W_hh2,
    const float* __restrict__ b_ih2, const float* __restrict__ b_hh2,
    bf16* __restrict__ Hhi, bf16* __restrict__ Hlo,
    const bf16* __restrict__ Whi, const bf16* __restrict__ Wlo,
    const float* __restrict__ b_fc,
    float* __restrict__ partial, float* __restrict__ inv_sum,
    float* __restrict__ out, int* __restrict__ flags)
{
    __shared__ alignas(16) bf16 H1h[2][16][40], H1l[2][16][40];
    __shared__ alignas(16) bf16 H2h[2][16][40], H2l[2][16][40];
    __shared__ alignas(16) float ring[2][16][16][33];

    int* prog = flags;          // [1]  half-chunks (16 steps) published
    int* scnt = flags + 16;     // [256]
    int* fin  = flags + 288;    // [256]

    const int bid = blockIdx.x;
    const int t   = threadIdx.x;

    if (bid == 0) {
        // ================= LSTM role (MFMA v2 + ring) =================
        const int w  = t >> 6;
        const int l  = t & 63;
        const int lr = l & 15, lq = l >> 4;

        const int garow = (lr & 3) * 32 + 4 * w + (lr >> 2);
        bf16x8 w1h, w1l, wi2h, wi2l, wh2h, wh2l;
        #pragma unroll
        for (int j = 0; j < 8; ++j) {
            float v1 = W_hh1[garow * D_H + lq * 8 + j];
            float v2 = W_ih2[garow * D_H + lq * 8 + j];
            float v3 = W_hh2[garow * D_H + lq * 8 + j];
            bf16 b1 = (bf16)v1, b2 = (bf16)v2, b3 = (bf16)v3;
            w1h[j]  = b1; w1l[j]  = (bf16)(v1 - (float)b1);
            wi2h[j] = b2; wi2l[j] = (bf16)(v2 - (float)b2);
            wh2h[j] = b3; wh2l[j] = (bf16)(v3 - (float)b3);
        }

        const int u = 4 * w + lq;
        f32x4 bias2;
        #pragma unroll
        for (int r = 0; r < 4; ++r)
            bias2[r] = b_ih2[r * 32 + u] + b_hh2[r * 32 + u];

        bf16x8 h1fh, h1fl, h2fh, h2fl;
        #pragma unroll
        for (int j = 0; j < 8; ++j) {
            h1fh[j] = (bf16)0.0f; h1fl[j] = (bf16)0.0f;
            h2fh[j] = (bf16)0.0f; h2fl[j] = (bf16)0.0f;
        }
        float c1 = 0.0f, c2 = 0.0f;

        const f32x4* G1v = (const f32x4*)G1d;
        f32x4 g1c = G1v[(long)w * 64 + l];

        #pragma unroll 1
        for (int s = 0; s < S_LEN; ++s) {
            const int p  = s & 1;
            const int sn = (s + 1 < S_LEN) ? s + 1 : s;
            f32x4 g1n = G1v[((long)sn * 8 + w) * 64 + l];

            // layer 1
            f32x4 d = __builtin_amdgcn_mfma_f32_16x16x32_bf16(w1h, h1fh, g1c, 0, 0, 0);
            d = __builtin_amdgcn_mfma_f32_16x16x32_bf16(w1l, h1fh, d, 0, 0, 0);
            d = __builtin_amdgcn_mfma_f32_16x16x32_bf16(w1h, h1fl, d, 0, 0, 0);
            float iv = sigf(d[0]), fv = sigf(d[1]);
            float gv = tanhfast(d[2]), ov = sigf(d[3]);
            c1 = fv * c1 + iv * gv;
            float h1 = ov * tanhfast(c1);
            bf16 hh = (bf16)h1;
            H1h[p][lr][u] = hh;
            H1l[p][lr][u] = (bf16)(h1 - (float)hh);
            __syncthreads();
            h1fh = *(const bf16x8*)&H1h[p][lr][lq * 8];
            h1fl = *(const bf16x8*)&H1l[p][lr][lq * 8];

            // layer 2
            f32x4 d2 = bias2;
            d2 = __builtin_amdgcn_mfma_f32_16x16x32_bf16(wi2h, h1fh, d2, 0, 0, 0);
            d2 = __builtin_amdgcn_mfma_f32_16x16x32_bf16(wi2l, h1fh, d2, 0, 0, 0);
            d2 = __builtin_amdgcn_mfma_f32_16x16x32_bf16(wi2h, h1fl, d2, 0, 0, 0);
            d2 = __builtin_amdgcn_mfma_f32_16x16x32_bf16(wh2h, h2fh, d2, 0, 0, 0);
            d2 = __builtin_amdgcn_mfma_f32_16x16x32_bf16(wh2l, h2fh, d2, 0, 0, 0);
            d2 = __builtin_amdgcn_mfma_f32_16x16x32_bf16(wh2h, h2fl, d2, 0, 0, 0);
            iv = sigf(d2[0]); fv = sigf(d2[1]);
            gv = tanhfast(d2[2]); ov = sigf(d2[3]);
            c2 = fv * c2 + iv * gv;
            float h2 = ov * tanhfast(c2);
            hh = (bf16)h2;
            H2h[p][lr][u] = hh;
            H2l[p][lr][u] = (bf16)(h2 - (float)hh);
            ring[(s >> 4) & 1][s & 15][lr][u] = h2;   // LDS only
            __syncthreads();
            h2fh = *(const bf16x8*)&H2h[p][lr][lq * 8];
            h2fl = *(const bf16x8*)&H2l[p][lr][lq * 8];

            if ((s & 15) == 15) {
                // flush half-chunk hcid to global as bf16 hi/lo
                const int hcid = s >> 4;
                const int rp = hcid & 1;
                const int pair = t >> 1;         // (step_local, batch)
                const int ss   = pair >> 4;
                const int bb2  = pair & 15;
                const int u0   = (t & 1) * 16;
                const float* src = &ring[rp][ss][bb2][u0];
                const long gbase = ((long)bb2 * S_LEN + hcid * 16 + ss) * D_H + u0;
                #pragma unroll
                for (int q = 0; q < 4; ++q) {
                    bf16x4 hv, lv;
                    #pragma unroll
                    for (int e = 0; e < 4; ++e) {
                        float v = src[q * 4 + e];
                        bf16 hb = (bf16)v;
                        hv[e] = hb;
                        lv[e] = (bf16)(v - (float)hb);
                    }
                    *(bf16x4*)(Hhi + gbase + q * 4) = hv;
                    *(bf16x4*)(Hlo + gbase + q * 4) = lv;
                }
                __syncthreads();   // drain flush stores block-wide
                if (t == 0)
                    __hip_atomic_store(prog, hcid + 1, __ATOMIC_RELEASE,
                                       __HIP_MEMORY_SCOPE_AGENT);
            }
            g1c = g1n;
        }
        return;
    }

    // ================= fc roles =================
    const int wid  = t >> 6;
    const int lane = t & 63;
    const int lr   = lane & 15, lq = lane >> 4;
    const f32x4 z  = {0.f, 0.f, 0.f, 0.f};

    if (bid <= NSB) {
        // ---- fc_sum + inv ----
        const int slot = (bid - 1) * 8 + wid;
        for (int it = slot; it < NWIN * NV1; it += NSB * 8) {
            const int wo = it / NV1, nv = it % NV1;
            const int c = wo >> 4, bb = wo & 15;

            while (__hip_atomic_load(prog, __ATOMIC_ACQUIRE,
                                     __HIP_MEMORY_SCOPE_AGENT) < 2 * c + 2) {
                __builtin_amdgcn_s_sleep(32);
            }

            const long t0 = (long)bb * S_LEN + (long)c * 32;
            const long arow0 = (t0 + lr) * D_H + lq * 8;
            const long arow1 = arow0 + 16 * D_H;
            bf16x8 a0h = *(const bf16x8*)(Hhi + arow0);
            bf16x8 a0l = *(const bf16x8*)(Hlo + arow0);
            bf16x8 a1h = *(const bf16x8*)(Hhi + arow1);
            bf16x8 a1l = *(const bf16x8*)(Hlo + arow1);

            f32x4 acc0 = z, acc1 = z;
            int v0 = nv * (VOCAB / NV1);
            for (int tile = 0; tile < VT1; ++tile, v0 += 16) {
                const long brow = (long)(v0 + lr) * D_H + lq * 8;
                bf16x8 bh = *(const bf16x8*)(Whi + brow);
                bf16x8 bl = *(const bf16x8*)(Wlo + brow);
                float bias = b_fc[v0 + lr];
                f32x4 d0 = __builtin_amdgcn_mfma_f32_16x16x32_bf16(a0h, bh, z, 0, 0, 0);
                d0 = __builtin_amdgcn_mfma_f32_16x16x32_bf16(a0l, bh, d0, 0, 0, 0);
                d0 = __builtin_amdgcn_mfma_f32_16x16x32_bf16(a0h, bl, d0, 0, 0, 0);
                f32x4 d1 = __builtin_amdgcn_mfma_f32_16x16x32_bf16(a1h, bh, z, 0, 0, 0);
                d1 = __builtin_amdgcn_mfma_f32_16x16x32_bf16(a1l, bh, d1, 0, 0, 0);
                d1 = __builtin_amdgcn_mfma_f32_16x16x32_bf16(a1h, bl, d1, 0, 0, 0);
                #pragma unroll
                for (int r = 0; r < 4; ++r) {
                    acc0[r] += __expf(d0[r] + bias);
                    acc1[r] += __expf(d1[r] + bias);
                }
            }
            #pragma unroll
            for (int m = 1; m < 16; m <<= 1) {
                #pragma unroll
                for (int r = 0; r < 4; ++r) {
                    acc0[r] += __shfl_xor(acc0[r], m, 64);
                    acc1[r] += __shfl_xor(acc1[r], m, 64);
                }
            }
            if (lr == 0) {
                #pragma unroll
                for (int r = 0; r < 4; ++r) {
                    partial[(long)nv * NTOK + t0 + lq * 4 + r]      = acc0[r];
                    partial[(long)nv * NTOK + t0 + 16 + lq * 4 + r] = acc1[r];
                }
            }
            int prev = 0;
            if (lane == 0) {
                prev = __hip_atomic_fetch_add(scnt + wo, 1, __ATOMIC_ACQ_REL,
                                              __HIP_MEMORY_SCOPE_AGENT);
            }
            prev = __shfl(prev, 0, 64);
            if (prev == NV1 - 1) {
                if (lane < 32) {
                    const long tk = t0 + lane;
                    float s = 0.0f;
                    #pragma unroll
                    for (int q = 0; q < NV1; ++q) s += partial[(long)q * NTOK + tk];
                    inv_sum[tk] = 1.0f / s;
                }
                if (lane == 0) {
                    __hip_atomic_store(fin + wo, 1, __ATOMIC_RELEASE,
                                       __HIP_MEMORY_SCOPE_AGENT);
                }
            }
        }
    } else {
        // ---- fc_out ----
        const int slot = (bid - 1 - NSB) * 8 + wid;
        for (int it = slot; it < NWIN * NVO; it += NOB * 8) {
            const int wo = it / NVO, nv = it % NVO;
            const int c = wo >> 4, bb = wo & 15;

            while (__hip_atomic_load(fin + wo, __ATOMIC_ACQUIRE,
                                     __HIP_MEMORY_SCOPE_AGENT) == 0) {
                __builtin_amdgcn_s_sleep(16);
            }

            const long t0 = (long)bb * S_LEN + (long)c * 32;
            const long arow0 = (t0 + lr) * D_H + lq * 8;
            const long arow1 = arow0 + 16 * D_H;
            bf16x8 a0h = *(const bf16x8*)(Hhi + arow0);
            bf16x8 a0l = *(const bf16x8*)(Hlo + arow0);
            bf16x8 a1h = *(const bf16x8*)(Hhi + arow1);
            bf16x8 a1l = *(const bf16x8*)(Hlo + arow1);

            float inv0[4], inv1[4];
            #pragma unroll
            for (int r = 0; r < 4; ++r) {
                inv0[r] = inv_sum[t0 + lq * 4 + r];
                inv1[r] = inv_sum[t0 + 16 + lq * 4 + r];
            }

            int v0 = nv * (VOCAB / NVO);
            for (int tile = 0; tile < VTO; ++tile, v0 += 16) {
                const long brow = (long)(v0 + lr) * D_H + lq * 8;
                bf16x8 bh = *(const bf16x8*)(Whi + brow);
                bf16x8 bl = *(const bf16x8*)(Wlo + brow);
                float bias = b_fc[v0 + lr];
                f32x4 d0 = __builtin_amdgcn_mfma_f32_16x16x32_bf16(a0h, bh, z, 0, 0, 0);
                d0 = __builtin_amdgcn_mfma_f32_16x16x32_bf16(a0l, bh, d0, 0, 0, 0);
                d0 = __builtin_amdgcn_mfma_f32_16x16x32_bf16(a0h, bl, d0, 0, 0, 0);
                f32x4 d1 = __builtin_amdgcn_mfma_f32_16x16x32_bf16(a1h, bh, z, 0, 0, 0);
                d1 = __builtin_amdgcn_mfma_f32_16x16x32_bf16(a1l, bh, d1, 0, 0, 0);
                d1 = __builtin_amdgcn_mfma_f32_16x16x32_bf16(a1h, bl, d1, 0, 0, 0);
                const int vcol = v0 + lr;
                #pragma unroll
                for (int r = 0; r < 4; ++r) {
                    out[(t0 + lq * 4 + r) * VOCAB + vcol] =
                        __expf(d0[r] + bias) * inv0[r];
                    out[(t0 + 16 + lq * 4 + r) * VOCAB + vcol] =
                        __expf(d1[r] + bias) * inv1[r];
                }
            }
        }
    }
}

// ---------------------------------------------------------------------------
extern "C" void kernel_launch(void* const* d_in, const int* in_sizes, int n_in,
                              void* d_out, int out_size, void* d_ws, size_t ws_size,
                              hipStream_t stream)
{
    const int*   x_ids = (const int*)d_in[0];
    const float* emb   = (const float*)d_in[1];
    const float* W_ih1 = (const float*)d_in[2];
    const float* W_hh1 = (const float*)d_in[3];
    const float* b_ih1 = (const float*)d_in[4];
    const float* b_hh1 = (const float*)d_in[5];
    const float* W_ih2 = (const float*)d_in[6];
    const float* W_hh2 = (const float*)d_in[7];
    const float* b_ih2 = (const float*)d_in[8];
    const float* b_hh2 = (const float*)d_in[9];
    const float* W_fc  = (const float*)d_in[10];
    const float* b_fc  = (const float*)d_in[11];
    float* out = (float*)d_out;

    char* p = (char*)d_ws;
    float* G1d     = (float*)p;            p += (long)S_LEN * 8 * 64 * 4 * 4; // 4 MB
    bf16* Hhi      = (bf16*)p;             p += (long)NTOK * D_H * 2;
    bf16* Hlo      = (bf16*)p;             p += (long)NTOK * D_H * 2;
    bf16* Whi      = (bf16*)p;             p += (long)VOCAB * D_H * 2;
    bf16* Wlo      = (bf16*)p;             p += (long)VOCAB * D_H * 2;
    float* partial = (float*)p;            p += (long)NV1 * NTOK * 4;
    float* inv_sum = (float*)p;            p += (long)NTOK * 4;
    int* flags     = (int*)p;              p += 544 * 4;

    k_cvt_w<<<VOCAB * D_H / (256 * 4), 256, 0, stream>>>(W_fc, Whi, Wlo);
    k_zero<<<1, 256, 0, stream>>>(flags);
    k_embed_gates<<<NTOK / 4, 128, 0, stream>>>(x_ids, emb, W_ih1, b_ih1, b_hh1, G1d);
    k_fused<<<GRID_F, 512, 0, stream>>>(
        G1d, W_hh1, W_ih2, W_hh2, b_ih2, b_hh2,
        Hhi, Hlo, Whi, Wlo, b_fc, partial, inv_sum, out, flags);
}

// Round 16
// 884.835 us; speedup vs baseline: 7.8583x; 7.8583x over previous
//
#include <hip/hip_runtime.h>
#include <math.h>

#define VOCAB 32000
#define D_IN  256
#define D_H   32
#define B_SZ  16
#define S_LEN 512
#define NTOK  (B_SZ * S_LEN)   // 8192
#define NV1   16               // vocab splits in sum pass
#define VT1   (VOCAB / 16 / NV1)   // 125 tiles of 16 rows
#define NV2   25               // vocab splits in out pass
#define VT2   (VOCAB / 16 / NV2)   // 80 tiles

typedef __bf16 bf16;
typedef __attribute__((ext_vector_type(8))) __bf16 bf16x8;
typedef __attribute__((ext_vector_type(4))) __bf16 bf16x4;
typedef __attribute__((ext_vector_type(4))) float f32x4;

__device__ __forceinline__ float sigf(float x) {
    return 1.0f / (1.0f + __expf(-x));
}

__device__ __forceinline__ float tanhfast(float x) {
    float ax = fabsf(x);
    float e = __expf(-2.0f * ax);
    float r = (1.0f - e) / (1.0f + e);
    return copysignf(r, x);
}

__device__ __forceinline__ float dot4(float4 a, float4 b) {
    return a.x * b.x + a.y * b.y + a.z * b.z + a.w * b.w;
}

// ---------------------------------------------------------------------------
// Convert W_fc (f32 [32000][32]) to bf16 hi/lo split arrays.
// ---------------------------------------------------------------------------
__global__ __launch_bounds__(256) void k_cvt_w(
    const float* __restrict__ W, bf16* __restrict__ Whi, bf16* __restrict__ Wlo)
{
    const long i = ((long)blockIdx.x * 256 + threadIdx.x) * 4;
    float4 w = *(const float4*)(W + i);
    bf16 h0 = (bf16)w.x, h1 = (bf16)w.y, h2 = (bf16)w.z, h3 = (bf16)w.w;
    bf16 l0 = (bf16)(w.x - (float)h0), l1 = (bf16)(w.y - (float)h1);
    bf16 l2 = (bf16)(w.z - (float)h2), l3 = (bf16)(w.w - (float)h3);
    bf16x4 hv = {h0, h1, h2, h3}, lv = {l0, l1, l2, l3};
    *(bf16x4*)(Whi + i) = hv;
    *(bf16x4*)(Wlo + i) = lv;
}

// ---------------------------------------------------------------------------
// Kernel A: input gates packed into the LSTM's D/C-fragment order (v2):
// float index (((s*8 + w)*64 + lane)*4 + gt), lane = lq*16 + b,
// holds G1[b][s][g = gt*32 + 4w + lq].
// ---------------------------------------------------------------------------
__global__ __launch_bounds__(128) void k_embed_gates(
    const int* __restrict__ x_ids, const float* __restrict__ emb,
    const float* __restrict__ W_ih1, const float* __restrict__ b_ih1,
    const float* __restrict__ b_hh1, float* __restrict__ G1d)
{
    __shared__ float4 xs[4][64];
    const int tid = threadIdx.x;
    const int t0  = blockIdx.x * 4;
    const int r0  = tid >> 6, j = tid & 63;
    #pragma unroll
    for (int rr = 0; rr < 2; ++rr) {
        int r = rr * 2 + r0;
        long id = x_ids[t0 + r];
        xs[r][j] = ((const float4*)(emb + id * (long)D_IN))[j];
    }
    __syncthreads();

    const int g = tid;
    const float4* wrow = (const float4*)(W_ih1 + (long)g * D_IN);
    const float bias = b_ih1[g] + b_hh1[g];
    float a0 = bias, a1 = bias, a2 = bias, a3 = bias;
    #pragma unroll 8
    for (int jj = 0; jj < 64; ++jj) {
        float4 w = wrow[jj];
        a0 += dot4(w, xs[0][jj]);
        a1 += dot4(w, xs[1][jj]);
        a2 += dot4(w, xs[2][jj]);
        a3 += dot4(w, xs[3][jj]);
    }
    const int b  = t0 >> 9;
    const int s0 = t0 & 511;
    const int gt = g >> 5;
    const int u  = g & 31;
    const int w  = u >> 2;
    const int lq = u & 3;
    const int lane = lq * 16 + b;
    float vals[4] = {a0, a1, a2, a3};
    #pragma unroll
    for (int k = 0; k < 4; ++k) {
        G1d[(((long)(s0 + k) * 8 + w) * 64 + lane) * 4 + gt] = vals[k];
    }
}

// ---------------------------------------------------------------------------
// Kernel B: MFMA LSTM v3 — L2 software-pipelined one step behind L1:
// iteration s computes L1(s) and L2(s-1), both reading only fragments from
// the PREVIOUS barrier -> 1 barrier/step and 9 near-independent MFMAs.
// h2 goes to a padded LDS ring; flushed to global every 16 steps.
// No global stores inside the per-step path.
// ---------------------------------------------------------------------------
__global__ __launch_bounds__(512, 1) void k_lstm_mfma(
    const float* __restrict__ G1d,
    const float* __restrict__ W_hh1,
    const float* __restrict__ W_ih2, const float* __restrict__ W_hh2,
    const float* __restrict__ b_ih2, const float* __restrict__ b_hh2,
    bf16* __restrict__ Hhi, bf16* __restrict__ Hlo)
{
    __shared__ alignas(16) bf16 H1h[2][16][40], H1l[2][16][40];
    __shared__ alignas(16) bf16 H2h[2][16][40], H2l[2][16][40];
    __shared__ alignas(16) float ring[2][16][16][36];   // 72 KB, bank-safe pad

    const int t  = threadIdx.x;
    const int w  = t >> 6;
    const int l  = t & 63;
    const int lr = l & 15, lq = l >> 4;

    // A-fragment row m=lr -> gate row g=(lr&3)*32 + 4w + (lr>>2)
    const int garow = (lr & 3) * 32 + 4 * w + (lr >> 2);
    bf16x8 w1h, w1l, wi2h, wi2l, wh2h, wh2l;
    #pragma unroll
    for (int j = 0; j < 8; ++j) {
        float v1 = W_hh1[garow * D_H + lq * 8 + j];
        float v2 = W_ih2[garow * D_H + lq * 8 + j];
        float v3 = W_hh2[garow * D_H + lq * 8 + j];
        bf16 b1 = (bf16)v1, b2 = (bf16)v2, b3 = (bf16)v3;
        w1h[j]  = b1; w1l[j]  = (bf16)(v1 - (float)b1);
        wi2h[j] = b2; wi2l[j] = (bf16)(v2 - (float)b2);
        wh2h[j] = b3; wh2l[j] = (bf16)(v3 - (float)b3);
    }

    const int u = 4 * w + lq;      // this lane's cell unit; batch = lr
    f32x4 bias2;
    #pragma unroll
    for (int r = 0; r < 4; ++r)
        bias2[r] = b_ih2[r * 32 + u] + b_hh2[r * 32 + u];

    bf16x8 h1fh, h1fl, h2fh, h2fl;
    #pragma unroll
    for (int j = 0; j < 8; ++j) {
        h1fh[j] = (bf16)0.0f; h1fl[j] = (bf16)0.0f;
        h2fh[j] = (bf16)0.0f; h2fl[j] = (bf16)0.0f;
    }
    float c1 = 0.0f, c2 = 0.0f;
    const f32x4 z = {0.f, 0.f, 0.f, 0.f};

    const f32x4* G1v = (const f32x4*)G1d;
    f32x4 g1c = G1v[(long)w * 64 + l];

    // flush chunk cc (steps 16cc..16cc+15) from ring to Hhi/Hlo as hi/lo bf16
    auto flush_chunk = [&](int cc) {
        const int rp   = cc & 1;
        const int pair = t >> 1;
        const int ss   = pair >> 4;
        const int bb   = pair & 15;
        const int u0   = (t & 1) * 16;
        const float* src = &ring[rp][ss][bb][u0];
        const long gbase = ((long)bb * S_LEN + cc * 16 + ss) * D_H + u0;
        #pragma unroll
        for (int q = 0; q < 4; ++q) {
            float4 v = *(const float4*)(src + q * 4);
            bf16 e0 = (bf16)v.x, e1 = (bf16)v.y, e2 = (bf16)v.z, e3 = (bf16)v.w;
            bf16x4 hv = {e0, e1, e2, e3};
            bf16x4 lv = {(bf16)(v.x - (float)e0), (bf16)(v.y - (float)e1),
                         (bf16)(v.z - (float)e2), (bf16)(v.w - (float)e3)};
            *(bf16x4*)(Hhi + gbase + q * 4) = hv;
            *(bf16x4*)(Hlo + gbase + q * 4) = lv;
        }
    };

    #pragma unroll 2
    for (int s = 0; s < S_LEN; ++s) {
        const int sn = (s + 1 < S_LEN) ? s + 1 : s;
        f32x4 g1n = G1v[((long)sn * 8 + w) * 64 + l];

        // ---- L1(s): 3 independent MFMAs ----
        f32x4 dA = __builtin_amdgcn_mfma_f32_16x16x32_bf16(w1h, h1fh, g1c, 0, 0, 0);
        f32x4 dB = __builtin_amdgcn_mfma_f32_16x16x32_bf16(w1l, h1fh, z, 0, 0, 0);
        f32x4 dC = __builtin_amdgcn_mfma_f32_16x16x32_bf16(w1h, h1fl, z, 0, 0, 0);

        // ---- L2(s-1): three independent 2-deep chains ----
        f32x4 eA, eB, eC;
        if (s > 0) {
            eA = __builtin_amdgcn_mfma_f32_16x16x32_bf16(wi2h, h1fh, bias2, 0, 0, 0);
            eA = __builtin_amdgcn_mfma_f32_16x16x32_bf16(wh2h, h2fh, eA, 0, 0, 0);
            eB = __builtin_amdgcn_mfma_f32_16x16x32_bf16(wi2l, h1fh, z, 0, 0, 0);
            eB = __builtin_amdgcn_mfma_f32_16x16x32_bf16(wh2l, h2fh, eB, 0, 0, 0);
            eC = __builtin_amdgcn_mfma_f32_16x16x32_bf16(wi2h, h1fl, z, 0, 0, 0);
            eC = __builtin_amdgcn_mfma_f32_16x16x32_bf16(wh2h, h2fl, eC, 0, 0, 0);
        }

        // L1 activations + cell update -> write H1[s&1]
        f32x4 d = (dA + dB) + dC;
        {
            float iv = sigf(d[0]), fv = sigf(d[1]);
            float gv = tanhfast(d[2]), ov = sigf(d[3]);
            c1 = fv * c1 + iv * gv;
            float h1 = ov * tanhfast(c1);
            bf16 hh = (bf16)h1;
            H1h[s & 1][lr][u] = hh;
            H1l[s & 1][lr][u] = (bf16)(h1 - (float)hh);
        }

        // L2 activations + cell update -> write H2[(s-1)&1] + ring
        if (s > 0) {
            f32x4 e = (eA + eB) + eC;
            float iv = sigf(e[0]), fv = sigf(e[1]);
            float gv = tanhfast(e[2]), ov = sigf(e[3]);
            c2 = fv * c2 + iv * gv;
            float h2 = ov * tanhfast(c2);
            bf16 hh = (bf16)h2;
            const int sp = (s - 1) & 1;
            H2h[sp][lr][u] = hh;
            H2l[sp][lr][u] = (bf16)(h2 - (float)hh);
            ring[((s - 1) >> 4) & 1][(s - 1) & 15][lr][u] = h2;
        }
        __syncthreads();

        h1fh = *(const bf16x8*)&H1h[s & 1][lr][lq * 8];
        h1fl = *(const bf16x8*)&H1l[s & 1][lr][lq * 8];
        if (s > 0) {
            const int sp = (s - 1) & 1;
            h2fh = *(const bf16x8*)&H2h[sp][lr][lq * 8];
            h2fl = *(const bf16x8*)&H2l[sp][lr][lq * 8];
        }

        if ((s & 15) == 0 && s > 0) {
            flush_chunk((s >> 4) - 1);   // steps s-16 .. s-1, all in ring
        }
        g1c = g1n;
    }

    // ---- epilogue: L2(S_LEN-1) ----
    {
        f32x4 eA = __builtin_amdgcn_mfma_f32_16x16x32_bf16(wi2h, h1fh, bias2, 0, 0, 0);
        eA = __builtin_amdgcn_mfma_f32_16x16x32_bf16(wh2h, h2fh, eA, 0, 0, 0);
        f32x4 eB = __builtin_amdgcn_mfma_f32_16x16x32_bf16(wi2l, h1fh, z, 0, 0, 0);
        eB = __builtin_amdgcn_mfma_f32_16x16x32_bf16(wh2l, h2fh, eB, 0, 0, 0);
        f32x4 eC = __builtin_amdgcn_mfma_f32_16x16x32_bf16(wi2h, h1fl, z, 0, 0, 0);
        eC = __builtin_amdgcn_mfma_f32_16x16x32_bf16(wh2h, h2fl, eC, 0, 0, 0);
        f32x4 e = (eA + eB) + eC;
        float iv = sigf(e[0]), fv = sigf(e[1]);
        float gv = tanhfast(e[2]), ov = sigf(e[3]);
        c2 = fv * c2 + iv * gv;
        float h2 = ov * tanhfast(c2);
        ring[((S_LEN - 1) >> 4) & 1][(S_LEN - 1) & 15][lr][u] = h2;
    }
    __syncthreads();
    flush_chunk((S_LEN >> 4) - 1);       // steps 496..511
}

// ---------------------------------------------------------------------------
// Kernel C1 (MFMA): partial softmax denominators.
// ---------------------------------------------------------------------------
__global__ __launch_bounds__(256) void k_fc_sum(
    const bf16* __restrict__ Hhi, const bf16* __restrict__ Hlo,
    const bf16* __restrict__ Whi, const bf16* __restrict__ Wlo,
    const float* __restrict__ b_fc, float* __restrict__ partial)
{
    const int lane = threadIdx.x & 63;
    const int wid  = threadIdx.x >> 6;
    const int tg   = blockIdx.x / NV1;
    const int nv   = blockIdx.x % NV1;
    const int t0   = tg * 128 + wid * 32;
    const int lr   = lane & 15, lq = lane >> 4;

    const long arow0 = (long)(t0 + lr) * D_H + lq * 8;
    const long arow1 = arow0 + 16 * D_H;
    bf16x8 a0h = *(const bf16x8*)(Hhi + arow0);
    bf16x8 a0l = *(const bf16x8*)(Hlo + arow0);
    bf16x8 a1h = *(const bf16x8*)(Hhi + arow1);
    bf16x8 a1l = *(const bf16x8*)(Hlo + arow1);

    f32x4 acc0 = {0.f, 0.f, 0.f, 0.f}, acc1 = {0.f, 0.f, 0.f, 0.f};
    const f32x4 z = {0.f, 0.f, 0.f, 0.f};
    int v0 = nv * (VOCAB / NV1);
    for (int tile = 0; tile < VT1; ++tile, v0 += 16) {
        const long brow = (long)(v0 + lr) * D_H + lq * 8;
        bf16x8 bh = *(const bf16x8*)(Whi + brow);
        bf16x8 bl = *(const bf16x8*)(Wlo + brow);
        float bias = b_fc[v0 + lr];
        f32x4 d0 = __builtin_amdgcn_mfma_f32_16x16x32_bf16(a0h, bh, z, 0, 0, 0);
        d0 = __builtin_amdgcn_mfma_f32_16x16x32_bf16(a0l, bh, d0, 0, 0, 0);
        d0 = __builtin_amdgcn_mfma_f32_16x16x32_bf16(a0h, bl, d0, 0, 0, 0);
        f32x4 d1 = __builtin_amdgcn_mfma_f32_16x16x32_bf16(a1h, bh, z, 0, 0, 0);
        d1 = __builtin_amdgcn_mfma_f32_16x16x32_bf16(a1l, bh, d1, 0, 0, 0);
        d1 = __builtin_amdgcn_mfma_f32_16x16x32_bf16(a1h, bl, d1, 0, 0, 0);
        #pragma unroll
        for (int r = 0; r < 4; ++r) {
            acc0[r] += __expf(d0[r] + bias);
            acc1[r] += __expf(d1[r] + bias);
        }
    }

    #pragma unroll
    for (int m = 1; m < 16; m <<= 1) {
        #pragma unroll
        for (int r = 0; r < 4; ++r) {
            acc0[r] += __shfl_xor(acc0[r], m, 64);
            acc1[r] += __shfl_xor(acc1[r], m, 64);
        }
    }
    if (lr == 0) {
        #pragma unroll
        for (int r = 0; r < 4; ++r) {
            partial[(long)nv * NTOK + t0 + lq * 4 + r]      = acc0[r];
            partial[(long)nv * NTOK + t0 + 16 + lq * 4 + r] = acc1[r];
        }
    }
}

__global__ __launch_bounds__(256) void k_inv(
    const float* __restrict__ partial, float* __restrict__ inv_sum)
{
    const int t = blockIdx.x * 256 + threadIdx.x;
    float s = 0.0f;
    #pragma unroll
    for (int nv = 0; nv < NV1; ++nv) s += partial[(long)nv * NTOK + t];
    inv_sum[t] = 1.0f / s;
}

// ---------------------------------------------------------------------------
// Kernel C2 (MFMA): recompute logits, write normalized softmax.
// ---------------------------------------------------------------------------
__global__ __launch_bounds__(256) void k_fc_out(
    const bf16* __restrict__ Hhi, const bf16* __restrict__ Hlo,
    const bf16* __restrict__ Whi, const bf16* __restrict__ Wlo,
    const float* __restrict__ b_fc, const float* __restrict__ inv_sum,
    float* __restrict__ out)
{
    const int lane = threadIdx.x & 63;
    const int wid  = threadIdx.x >> 6;
    const int tg   = blockIdx.x / NV2;
    const int nv   = blockIdx.x % NV2;
    const int t0   = tg * 128 + wid * 32;
    const int lr   = lane & 15, lq = lane >> 4;

    const long arow0 = (long)(t0 + lr) * D_H + lq * 8;
    const long arow1 = arow0 + 16 * D_H;
    bf16x8 a0h = *(const bf16x8*)(Hhi + arow0);
    bf16x8 a0l = *(const bf16x8*)(Hlo + arow0);
    bf16x8 a1h = *(const bf16x8*)(Hhi + arow1);
    bf16x8 a1l = *(const bf16x8*)(Hlo + arow1);

    float inv0[4], inv1[4];
    #pragma unroll
    for (int r = 0; r < 4; ++r) {
        inv0[r] = inv_sum[t0 + lq * 4 + r];
        inv1[r] = inv_sum[t0 + 16 + lq * 4 + r];
    }

    const f32x4 z = {0.f, 0.f, 0.f, 0.f};
    int v0 = nv * (VOCAB / NV2);
    for (int tile = 0; tile < VT2; ++tile, v0 += 16) {
        const long brow = (long)(v0 + lr) * D_H + lq * 8;
        bf16x8 bh = *(const bf16x8*)(Whi + brow);
        bf16x8 bl = *(const bf16x8*)(Wlo + brow);
        float bias = b_fc[v0 + lr];
        f32x4 d0 = __builtin_amdgcn_mfma_f32_16x16x32_bf16(a0h, bh, z, 0, 0, 0);
        d0 = __builtin_amdgcn_mfma_f32_16x16x32_bf16(a0l, bh, d0, 0, 0, 0);
        d0 = __builtin_amdgcn_mfma_f32_16x16x32_bf16(a0h, bl, d0, 0, 0, 0);
        f32x4 d1 = __builtin_amdgcn_mfma_f32_16x16x32_bf16(a1h, bh, z, 0, 0, 0);
        d1 = __builtin_amdgcn_mfma_f32_16x16x32_bf16(a1l, bh, d1, 0, 0, 0);
        d1 = __builtin_amdgcn_mfma_f32_16x16x32_bf16(a1h, bl, d1, 0, 0, 0);
        const int vcol = v0 + lr;
        #pragma unroll
        for (int r = 0; r < 4; ++r) {
            out[(long)(t0 + lq * 4 + r) * VOCAB + vcol] =
                __expf(d0[r] + bias) * inv0[r];
            out[(long)(t0 + 16 + lq * 4 + r) * VOCAB + vcol] =
                __expf(d1[r] + bias) * inv1[r];
        }
    }
}

// ---------------------------------------------------------------------------
extern "C" void kernel_launch(void* const* d_in, const int* in_sizes, int n_in,
                              void* d_out, int out_size, void* d_ws, size_t ws_size,
                              hipStream_t stream)
{
    const int*   x_ids = (const int*)d_in[0];
    const float* emb   = (const float*)d_in[1];
    const float* W_ih1 = (const float*)d_in[2];
    const float* W_hh1 = (const float*)d_in[3];
    const float* b_ih1 = (const float*)d_in[4];
    const float* b_hh1 = (const float*)d_in[5];
    const float* W_ih2 = (const float*)d_in[6];
    const float* W_hh2 = (const float*)d_in[7];
    const float* b_ih2 = (const float*)d_in[8];
    const float* b_hh2 = (const float*)d_in[9];
    const float* W_fc  = (const float*)d_in[10];
    const float* b_fc  = (const float*)d_in[11];
    float* out = (float*)d_out;

    char* p = (char*)d_ws;
    float* G1d     = (float*)p;            p += (long)S_LEN * 8 * 64 * 4 * 4; // 4 MB
    bf16* Hhi      = (bf16*)p;             p += (long)NTOK * D_H * 2;   // 512 KB
    bf16* Hlo      = (bf16*)p;             p += (long)NTOK * D_H * 2;   // 512 KB
    bf16* Whi      = (bf16*)p;             p += (long)VOCAB * D_H * 2;  // 2 MB
    bf16* Wlo      = (bf16*)p;             p += (long)VOCAB * D_H * 2;  // 2 MB
    float* partial = (float*)p;            p += (long)NV1 * NTOK * 4;   // 512 KB
    float* inv_sum = (float*)p;            p += (long)NTOK * 4;         // 32 KB

    k_cvt_w<<<VOCAB * D_H / (256 * 4), 256, 0, stream>>>(W_fc, Whi, Wlo);
    k_embed_gates<<<NTOK / 4, 128, 0, stream>>>(x_ids, emb, W_ih1, b_ih1, b_hh1, G1d);
    k_lstm_mfma<<<1, 512, 0, stream>>>(G1d, W_hh1, W_ih2, W_hh2, b_ih2, b_hh2, Hhi, Hlo);
    k_fc_sum<<<(NTOK / 128) * NV1, 256, 0, stream>>>(Hhi, Hlo, Whi, Wlo, b_fc, partial);
    k_inv<<<NTOK / 256, 256, 0, stream>>>(partial, inv_sum);
    k_fc_out<<<(NTOK / 128) * NV2, 256, 0, stream>>>(Hhi, Hlo, Whi, Wlo, b_fc, inv_sum, out);
}

// Round 17
// 696.989 us; speedup vs baseline: 9.9762x; 1.2695x over previous
//
#include <hip/hip_runtime.h>
#include <math.h>

#define VOCAB 32000
#define D_IN  256
#define D_H   32
#define B_SZ  16
#define S_LEN 512
#define NTOK  (B_SZ * S_LEN)   // 8192
#define NV1   16               // vocab splits in sum pass
#define VT1   (VOCAB / 16 / NV1)   // 125 tiles of 16 rows
#define NV2   25               // vocab splits in out pass
#define VT2   (VOCAB / 16 / NV2)   // 80 tiles

typedef __bf16 bf16;
typedef __attribute__((ext_vector_type(8))) __bf16 bf16x8;
typedef __attribute__((ext_vector_type(4))) __bf16 bf16x4;
typedef __attribute__((ext_vector_type(4))) float f32x4;

__device__ __forceinline__ float rcpf(float x) {
    return __builtin_amdgcn_rcpf(x);
}

__device__ __forceinline__ float sigf(float x) {
    return rcpf(1.0f + __expf(-x));
}

__device__ __forceinline__ float tanhfast(float x) {
    float ax = fabsf(x);
    float e = __expf(-2.0f * ax);
    float r = (1.0f - e) * rcpf(1.0f + e);
    return copysignf(r, x);
}

__device__ __forceinline__ float dot4(float4 a, float4 b) {
    return a.x * b.x + a.y * b.y + a.z * b.z + a.w * b.w;
}

// ---------------------------------------------------------------------------
// Convert W_fc (f32 [32000][32]) to bf16 hi/lo split arrays.
// ---------------------------------------------------------------------------
__global__ __launch_bounds__(256) void k_cvt_w(
    const float* __restrict__ W, bf16* __restrict__ Whi, bf16* __restrict__ Wlo)
{
    const long i = ((long)blockIdx.x * 256 + threadIdx.x) * 4;
    float4 w = *(const float4*)(W + i);
    bf16 h0 = (bf16)w.x, h1 = (bf16)w.y, h2 = (bf16)w.z, h3 = (bf16)w.w;
    bf16 l0 = (bf16)(w.x - (float)h0), l1 = (bf16)(w.y - (float)h1);
    bf16 l2 = (bf16)(w.z - (float)h2), l3 = (bf16)(w.w - (float)h3);
    bf16x4 hv = {h0, h1, h2, h3}, lv = {l0, l1, l2, l3};
    *(bf16x4*)(Whi + i) = hv;
    *(bf16x4*)(Wlo + i) = lv;
}

// ---------------------------------------------------------------------------
// Kernel A: input gates packed into the LSTM's D/C-fragment order (v2):
// float index (((s*8 + w)*64 + lane)*4 + gt), lane = lq*16 + b,
// holds G1[b][s][g = gt*32 + 4w + lq].
// ---------------------------------------------------------------------------
__global__ __launch_bounds__(128) void k_embed_gates(
    const int* __restrict__ x_ids, const float* __restrict__ emb,
    const float* __restrict__ W_ih1, const float* __restrict__ b_ih1,
    const float* __restrict__ b_hh1, float* __restrict__ G1d)
{
    __shared__ float4 xs[4][64];
    const int tid = threadIdx.x;
    const int t0  = blockIdx.x * 4;
    const int r0  = tid >> 6, j = tid & 63;
    #pragma unroll
    for (int rr = 0; rr < 2; ++rr) {
        int r = rr * 2 + r0;
        long id = x_ids[t0 + r];
        xs[r][j] = ((const float4*)(emb + id * (long)D_IN))[j];
    }
    __syncthreads();

    const int g = tid;
    const float4* wrow = (const float4*)(W_ih1 + (long)g * D_IN);
    const float bias = b_ih1[g] + b_hh1[g];
    float a0 = bias, a1 = bias, a2 = bias, a3 = bias;
    #pragma unroll 8
    for (int jj = 0; jj < 64; ++jj) {
        float4 w = wrow[jj];
        a0 += dot4(w, xs[0][jj]);
        a1 += dot4(w, xs[1][jj]);
        a2 += dot4(w, xs[2][jj]);
        a3 += dot4(w, xs[3][jj]);
    }
    const int b  = t0 >> 9;
    const int s0 = t0 & 511;
    const int gt = g >> 5;
    const int u  = g & 31;
    const int w  = u >> 2;
    const int lq = u & 3;
    const int lane = lq * 16 + b;
    float vals[4] = {a0, a1, a2, a3};
    #pragma unroll
    for (int k = 0; k < 4; ++k) {
        G1d[(((long)(s0 + k) * 8 + w) * 64 + lane) * 4 + gt] = vals[k];
    }
}

// ---------------------------------------------------------------------------
// Kernel B: MFMA LSTM v4 = v3 (1 barrier/step, L2 pipelined one step behind)
// + chunked G1 register staging (8 steps per chunk, double-buffered ->
//   the barrier's vmcnt(0) drain hits once per 8 steps, not every step)
// + v_rcp_f32 activations (no f32 div sequences).
// ---------------------------------------------------------------------------
__global__ __launch_bounds__(512, 1) void k_lstm_mfma(
    const float* __restrict__ G1d,
    const float* __restrict__ W_hh1,
    const float* __restrict__ W_ih2, const float* __restrict__ W_hh2,
    const float* __restrict__ b_ih2, const float* __restrict__ b_hh2,
    bf16* __restrict__ Hhi, bf16* __restrict__ Hlo)
{
    __shared__ alignas(16) bf16 H1h[2][16][40], H1l[2][16][40];
    __shared__ alignas(16) bf16 H2h[2][16][40], H2l[2][16][40];
    __shared__ alignas(16) float ring[2][16][16][36];   // 72 KB

    const int t  = threadIdx.x;
    const int w  = t >> 6;
    const int l  = t & 63;
    const int lr = l & 15, lq = l >> 4;

    const int garow = (lr & 3) * 32 + 4 * w + (lr >> 2);
    bf16x8 w1h, w1l, wi2h, wi2l, wh2h, wh2l;
    #pragma unroll
    for (int j = 0; j < 8; ++j) {
        float v1 = W_hh1[garow * D_H + lq * 8 + j];
        float v2 = W_ih2[garow * D_H + lq * 8 + j];
        float v3 = W_hh2[garow * D_H + lq * 8 + j];
        bf16 b1 = (bf16)v1, b2 = (bf16)v2, b3 = (bf16)v3;
        w1h[j]  = b1; w1l[j]  = (bf16)(v1 - (float)b1);
        wi2h[j] = b2; wi2l[j] = (bf16)(v2 - (float)b2);
        wh2h[j] = b3; wh2l[j] = (bf16)(v3 - (float)b3);
    }

    const int u = 4 * w + lq;      // this lane's cell unit; batch = lr
    f32x4 bias2;
    #pragma unroll
    for (int r = 0; r < 4; ++r)
        bias2[r] = b_ih2[r * 32 + u] + b_hh2[r * 32 + u];

    bf16x8 h1fh, h1fl, h2fh, h2fl;
    #pragma unroll
    for (int j = 0; j < 8; ++j) {
        h1fh[j] = (bf16)0.0f; h1fl[j] = (bf16)0.0f;
        h2fh[j] = (bf16)0.0f; h2fl[j] = (bf16)0.0f;
    }
    float c1 = 0.0f, c2 = 0.0f;
    const f32x4 z = {0.f, 0.f, 0.f, 0.f};

    const f32x4* G1v = (const f32x4*)G1d;

    // flush chunk cc (steps 16cc..16cc+15) from ring to Hhi/Hlo as hi/lo bf16
    auto flush_chunk = [&](int cc) {
        const int rp   = cc & 1;
        const int pair = t >> 1;
        const int ss   = pair >> 4;
        const int bb   = pair & 15;
        const int u0   = (t & 1) * 16;
        const float* src = &ring[rp][ss][bb][u0];
        const long gbase = ((long)bb * S_LEN + cc * 16 + ss) * D_H + u0;
        #pragma unroll
        for (int q = 0; q < 4; ++q) {
            float4 v = *(const float4*)(src + q * 4);
            bf16 e0 = (bf16)v.x, e1 = (bf16)v.y, e2 = (bf16)v.z, e3 = (bf16)v.w;
            bf16x4 hv = {e0, e1, e2, e3};
            bf16x4 lv = {(bf16)(v.x - (float)e0), (bf16)(v.y - (float)e1),
                         (bf16)(v.z - (float)e2), (bf16)(v.w - (float)e3)};
            *(bf16x4*)(Hhi + gbase + q * 4) = hv;
            *(bf16x4*)(Hlo + gbase + q * 4) = lv;
        }
    };

    // one LSTM step (v3 body): L1(s) + L2(s-1), 1 barrier
    auto step = [&](int s, f32x4 g1c) {
        // L1(s): 3 independent MFMAs
        f32x4 dA = __builtin_amdgcn_mfma_f32_16x16x32_bf16(w1h, h1fh, g1c, 0, 0, 0);
        f32x4 dB = __builtin_amdgcn_mfma_f32_16x16x32_bf16(w1l, h1fh, z, 0, 0, 0);
        f32x4 dC = __builtin_amdgcn_mfma_f32_16x16x32_bf16(w1h, h1fl, z, 0, 0, 0);

        // L2(s-1): three independent 2-deep chains
        f32x4 eA, eB, eC;
        if (s > 0) {
            eA = __builtin_amdgcn_mfma_f32_16x16x32_bf16(wi2h, h1fh, bias2, 0, 0, 0);
            eA = __builtin_amdgcn_mfma_f32_16x16x32_bf16(wh2h, h2fh, eA, 0, 0, 0);
            eB = __builtin_amdgcn_mfma_f32_16x16x32_bf16(wi2l, h1fh, z, 0, 0, 0);
            eB = __builtin_amdgcn_mfma_f32_16x16x32_bf16(wh2l, h2fh, eB, 0, 0, 0);
            eC = __builtin_amdgcn_mfma_f32_16x16x32_bf16(wi2h, h1fl, z, 0, 0, 0);
            eC = __builtin_amdgcn_mfma_f32_16x16x32_bf16(wh2h, h2fl, eC, 0, 0, 0);
        }

        f32x4 d = (dA + dB) + dC;
        {
            float iv = sigf(d[0]), fv = sigf(d[1]);
            float gv = tanhfast(d[2]), ov = sigf(d[3]);
            c1 = fv * c1 + iv * gv;
            float h1 = ov * tanhfast(c1);
            bf16 hh = (bf16)h1;
            H1h[s & 1][lr][u] = hh;
            H1l[s & 1][lr][u] = (bf16)(h1 - (float)hh);
        }

        if (s > 0) {
            f32x4 e = (eA + eB) + eC;
            float iv = sigf(e[0]), fv = sigf(e[1]);
            float gv = tanhfast(e[2]), ov = sigf(e[3]);
            c2 = fv * c2 + iv * gv;
            float h2 = ov * tanhfast(c2);
            bf16 hh = (bf16)h2;
            const int sp = (s - 1) & 1;
            H2h[sp][lr][u] = hh;
            H2l[sp][lr][u] = (bf16)(h2 - (float)hh);
            ring[((s - 1) >> 4) & 1][(s - 1) & 15][lr][u] = h2;
        }
        __syncthreads();

        h1fh = *(const bf16x8*)&H1h[s & 1][lr][lq * 8];
        h1fl = *(const bf16x8*)&H1l[s & 1][lr][lq * 8];
        if (s > 0) {
            const int sp = (s - 1) & 1;
            h2fh = *(const bf16x8*)&H2h[sp][lr][lq * 8];
            h2fl = *(const bf16x8*)&H2l[sp][lr][lq * 8];
        }

        if ((s & 15) == 0 && s > 0) {
            flush_chunk((s >> 4) - 1);
        }
    };

    // ---- chunked G1 staging: 64 chunks of 8 steps, double-buffered ----
    f32x4 bufA[8], bufB[8];
    #pragma unroll
    for (int k = 0; k < 8; ++k)
        bufA[k] = G1v[((long)k * 8 + w) * 64 + l];

    #pragma unroll 1
    for (int c = 0; c < 64; c += 2) {
        {   // even chunk: compute from bufA, prefetch chunk c+1 into bufB
            const int cn = c + 1;
            #pragma unroll
            for (int k = 0; k < 8; ++k)
                bufB[k] = G1v[((long)(cn * 8 + k) * 8 + w) * 64 + l];
            #pragma unroll
            for (int k = 0; k < 8; ++k)
                step(c * 8 + k, bufA[k]);
        }
        {   // odd chunk: compute from bufB, prefetch chunk c+2 into bufA
            const int cn = (c + 2 < 64) ? c + 2 : 0;
            #pragma unroll
            for (int k = 0; k < 8; ++k)
                bufA[k] = G1v[((long)(cn * 8 + k) * 8 + w) * 64 + l];
            #pragma unroll
            for (int k = 0; k < 8; ++k)
                step((c + 1) * 8 + k, bufB[k]);
        }
    }

    // ---- epilogue: L2(S_LEN-1) ----
    {
        f32x4 eA = __builtin_amdgcn_mfma_f32_16x16x32_bf16(wi2h, h1fh, bias2, 0, 0, 0);
        eA = __builtin_amdgcn_mfma_f32_16x16x32_bf16(wh2h, h2fh, eA, 0, 0, 0);
        f32x4 eB = __builtin_amdgcn_mfma_f32_16x16x32_bf16(wi2l, h1fh, z, 0, 0, 0);
        eB = __builtin_amdgcn_mfma_f32_16x16x32_bf16(wh2l, h2fh, eB, 0, 0, 0);
        f32x4 eC = __builtin_amdgcn_mfma_f32_16x16x32_bf16(wi2h, h1fl, z, 0, 0, 0);
        eC = __builtin_amdgcn_mfma_f32_16x16x32_bf16(wh2h, h2fl, eC, 0, 0, 0);
        f32x4 e = (eA + eB) + eC;
        float iv = sigf(e[0]), fv = sigf(e[1]);
        float gv = tanhfast(e[2]), ov = sigf(e[3]);
        c2 = fv * c2 + iv * gv;
        float h2 = ov * tanhfast(c2);
        ring[((S_LEN - 1) >> 4) & 1][(S_LEN - 1) & 15][lr][u] = h2;
    }
    __syncthreads();
    flush_chunk((S_LEN >> 4) - 1);       // steps 496..511
}

// ---------------------------------------------------------------------------
// Kernel C1 (MFMA): partial softmax denominators.
// ---------------------------------------------------------------------------
__global__ __launch_bounds__(256) void k_fc_sum(
    const bf16* __restrict__ Hhi, const bf16* __restrict__ Hlo,
    const bf16* __restrict__ Whi, const bf16* __restrict__ Wlo,
    const float* __restrict__ b_fc, float* __restrict__ partial)
{
    const int lane = threadIdx.x & 63;
    const int wid  = threadIdx.x >> 6;
    const int tg   = blockIdx.x / NV1;
    const int nv   = blockIdx.x % NV1;
    const int t0   = tg * 128 + wid * 32;
    const int lr   = lane & 15, lq = lane >> 4;

    const long arow0 = (long)(t0 + lr) * D_H + lq * 8;
    const long arow1 = arow0 + 16 * D_H;
    bf16x8 a0h = *(const bf16x8*)(Hhi + arow0);
    bf16x8 a0l = *(const bf16x8*)(Hlo + arow0);
    bf16x8 a1h = *(const bf16x8*)(Hhi + arow1);
    bf16x8 a1l = *(const bf16x8*)(Hlo + arow1);

    f32x4 acc0 = {0.f, 0.f, 0.f, 0.f}, acc1 = {0.f, 0.f, 0.f, 0.f};
    const f32x4 z = {0.f, 0.f, 0.f, 0.f};
    int v0 = nv * (VOCAB / NV1);
    for (int tile = 0; tile < VT1; ++tile, v0 += 16) {
        const long brow = (long)(v0 + lr) * D_H + lq * 8;
        bf16x8 bh = *(const bf16x8*)(Whi + brow);
        bf16x8 bl = *(const bf16x8*)(Wlo + brow);
        float bias = b_fc[v0 + lr];
        f32x4 d0 = __builtin_amdgcn_mfma_f32_16x16x32_bf16(a0h, bh, z, 0, 0, 0);
        d0 = __builtin_amdgcn_mfma_f32_16x16x32_bf16(a0l, bh, d0, 0, 0, 0);
        d0 = __builtin_amdgcn_mfma_f32_16x16x32_bf16(a0h, bl, d0, 0, 0, 0);
        f32x4 d1 = __builtin_amdgcn_mfma_f32_16x16x32_bf16(a1h, bh, z, 0, 0, 0);
        d1 = __builtin_amdgcn_mfma_f32_16x16x32_bf16(a1l, bh, d1, 0, 0, 0);
        d1 = __builtin_amdgcn_mfma_f32_16x16x32_bf16(a1h, bl, d1, 0, 0, 0);
        #pragma unroll
        for (int r = 0; r < 4; ++r) {
            acc0[r] += __expf(d0[r] + bias);
            acc1[r] += __expf(d1[r] + bias);
        }
    }

    #pragma unroll
    for (int m = 1; m < 16; m <<= 1) {
        #pragma unroll
        for (int r = 0; r < 4; ++r) {
            acc0[r] += __shfl_xor(acc0[r], m, 64);
            acc1[r] += __shfl_xor(acc1[r], m, 64);
        }
    }
    if (lr == 0) {
        #pragma unroll
        for (int r = 0; r < 4; ++r) {
            partial[(long)nv * NTOK + t0 + lq * 4 + r]      = acc0[r];
            partial[(long)nv * NTOK + t0 + 16 + lq * 4 + r] = acc1[r];
        }
    }
}

__global__ __launch_bounds__(256) void k_inv(
    const float* __restrict__ partial, float* __restrict__ inv_sum)
{
    const int t = blockIdx.x * 256 + threadIdx.x;
    float s = 0.0f;
    #pragma unroll
    for (int nv = 0; nv < NV1; ++nv) s += partial[(long)nv * NTOK + t];
    inv_sum[t] = 1.0f / s;
}

// ---------------------------------------------------------------------------
// Kernel C2 (MFMA): recompute logits, write normalized softmax.
// ---------------------------------------------------------------------------
__global__ __launch_bounds__(256) void k_fc_out(
    const bf16* __restrict__ Hhi, const bf16* __restrict__ Hlo,
    const bf16* __restrict__ Whi, const bf16* __restrict__ Wlo,
    const float* __restrict__ b_fc, const float* __restrict__ inv_sum,
    float* __restrict__ out)
{
    const int lane = threadIdx.x & 63;
    const int wid  = threadIdx.x >> 6;
    const int tg   = blockIdx.x / NV2;
    const int nv   = blockIdx.x % NV2;
    const int t0   = tg * 128 + wid * 32;
    const int lr   = lane & 15, lq = lane >> 4;

    const long arow0 = (long)(t0 + lr) * D_H + lq * 8;
    const long arow1 = arow0 + 16 * D_H;
    bf16x8 a0h = *(const bf16x8*)(Hhi + arow0);
    bf16x8 a0l = *(const bf16x8*)(Hlo + arow0);
    bf16x8 a1h = *(const bf16x8*)(Hhi + arow1);
    bf16x8 a1l = *(const bf16x8*)(Hlo + arow1);

    float inv0[4], inv1[4];
    #pragma unroll
    for (int r = 0; r < 4; ++r) {
        inv0[r] = inv_sum[t0 + lq * 4 + r];
        inv1[r] = inv_sum[t0 + 16 + lq * 4 + r];
    }

    const f32x4 z = {0.f, 0.f, 0.f, 0.f};
    int v0 = nv * (VOCAB / NV2);
    for (int tile = 0; tile < VT2; ++tile, v0 += 16) {
        const long brow = (long)(v0 + lr) * D_H + lq * 8;
        bf16x8 bh = *(const bf16x8*)(Whi + brow);
        bf16x8 bl = *(const bf16x8*)(Wlo + brow);
        float bias = b_fc[v0 + lr];
        f32x4 d0 = __builtin_amdgcn_mfma_f32_16x16x32_bf16(a0h, bh, z, 0, 0, 0);
        d0 = __builtin_amdgcn_mfma_f32_16x16x32_bf16(a0l, bh, d0, 0, 0, 0);
        d0 = __builtin_amdgcn_mfma_f32_16x16x32_bf16(a0h, bl, d0, 0, 0, 0);
        f32x4 d1 = __builtin_amdgcn_mfma_f32_16x16x32_bf16(a1h, bh, z, 0, 0, 0);
        d1 = __builtin_amdgcn_mfma_f32_16x16x32_bf16(a1l, bh, d1, 0, 0, 0);
        d1 = __builtin_amdgcn_mfma_f32_16x16x32_bf16(a1h, bl, d1, 0, 0, 0);
        const int vcol = v0 + lr;
        #pragma unroll
        for (int r = 0; r < 4; ++r) {
            out[(long)(t0 + lq * 4 + r) * VOCAB + vcol] =
                __expf(d0[r] + bias) * inv0[r];
            out[(long)(t0 + 16 + lq * 4 + r) * VOCAB + vcol] =
                __expf(d1[r] + bias) * inv1[r];
        }
    }
}

// ---------------------------------------------------------------------------
extern "C" void kernel_launch(void* const* d_in, const int* in_sizes, int n_in,
                              void* d_out, int out_size, void* d_ws, size_t ws_size,
                              hipStream_t stream)
{
    const int*   x_ids = (const int*)d_in[0];
    const float* emb   = (const float*)d_in[1];
    const float* W_ih1 = (const float*)d_in[2];
    const float* W_hh1 = (const float*)d_in[3];
    const float* b_ih1 = (const float*)d_in[4];
    const float* b_hh1 = (const float*)d_in[5];
    const float* W_ih2 = (const float*)d_in[6];
    const float* W_hh2 = (const float*)d_in[7];
    const float* b_ih2 = (const float*)d_in[8];
    const float* b_hh2 = (const float*)d_in[9];
    const float* W_fc  = (const float*)d_in[10];
    const float* b_fc  = (const float*)d_in[11];
    float* out = (float*)d_out;

    char* p = (char*)d_ws;
    float* G1d     = (float*)p;            p += (long)S_LEN * 8 * 64 * 4 * 4; // 4 MB
    bf16* Hhi      = (bf16*)p;             p += (long)NTOK * D_H * 2;   // 512 KB
    bf16* Hlo      = (bf16*)p;             p += (long)NTOK * D_H * 2;   // 512 KB
    bf16* Whi      = (bf16*)p;             p += (long)VOCAB * D_H * 2;  // 2 MB
    bf16* Wlo      = (bf16*)p;             p += (long)VOCAB * D_H * 2;  // 2 MB
    float* partial = (float*)p;            p += (long)NV1 * NTOK * 4;   // 512 KB
    float* inv_sum = (float*)p;            p += (long)NTOK * 4;         // 32 KB

    k_cvt_w<<<VOCAB * D_H / (256 * 4), 256, 0, stream>>>(W_fc, Whi, Wlo);
    k_embed_gates<<<NTOK / 4, 128, 0, stream>>>(x_ids, emb, W_ih1, b_ih1, b_hh1, G1d);
    k_lstm_mfma<<<1, 512, 0, stream>>>(G1d, W_hh1, W_ih2, W_hh2, b_ih2, b_hh2, Hhi, Hlo);
    k_fc_sum<<<(NTOK / 128) * NV1, 256, 0, stream>>>(Hhi, Hlo, Whi, Wlo, b_fc, partial);
    k_inv<<<NTOK / 256, 256, 0, stream>>>(partial, inv_sum);
    k_fc_out<<<(NTOK / 128) * NV2, 256, 0, stream>>>(Hhi, Hlo, Whi, Wlo, b_fc, inv_sum, out);
}

// Round 18
// 652.058 us; speedup vs baseline: 10.6636x; 1.0689x over previous
//
#include <hip/hip_runtime.h>
#include <math.h>

#define VOCAB 32000
#define D_IN  256
#define D_H   32
#define B_SZ  16
#define S_LEN 512
#define NTOK  (B_SZ * S_LEN)   // 8192
#define NV1   16               // vocab splits in sum pass
#define VT1   (VOCAB / 16 / NV1)   // 125 tiles of 16 rows
#define NV2   25               // vocab splits in out pass
#define VT2   (VOCAB / 16 / NV2)   // 80 tiles

typedef __bf16 bf16;
typedef __attribute__((ext_vector_type(8))) __bf16 bf16x8;
typedef __attribute__((ext_vector_type(4))) __bf16 bf16x4;
typedef __attribute__((ext_vector_type(4))) float f32x4;

__device__ __forceinline__ float rcpf(float x) {
    return __builtin_amdgcn_rcpf(x);
}

__device__ __forceinline__ float sigf(float x) {
    return rcpf(1.0f + __expf(-x));
}

__device__ __forceinline__ float tanhfast(float x) {
    float ax = fabsf(x);
    float e = __expf(-2.0f * ax);
    float r = (1.0f - e) * rcpf(1.0f + e);
    return copysignf(r, x);
}

__device__ __forceinline__ float dot4(float4 a, float4 b) {
    return a.x * b.x + a.y * b.y + a.z * b.z + a.w * b.w;
}

// ---------------------------------------------------------------------------
// Convert W_fc (f32 [32000][32]) to bf16 hi/lo split arrays.
// ---------------------------------------------------------------------------
__global__ __launch_bounds__(256) void k_cvt_w(
    const float* __restrict__ W, bf16* __restrict__ Whi, bf16* __restrict__ Wlo)
{
    const long i = ((long)blockIdx.x * 256 + threadIdx.x) * 4;
    float4 w = *(const float4*)(W + i);
    bf16 h0 = (bf16)w.x, h1 = (bf16)w.y, h2 = (bf16)w.z, h3 = (bf16)w.w;
    bf16 l0 = (bf16)(w.x - (float)h0), l1 = (bf16)(w.y - (float)h1);
    bf16 l2 = (bf16)(w.z - (float)h2), l3 = (bf16)(w.w - (float)h3);
    bf16x4 hv = {h0, h1, h2, h3}, lv = {l0, l1, l2, l3};
    *(bf16x4*)(Whi + i) = hv;
    *(bf16x4*)(Wlo + i) = lv;
}

// ---------------------------------------------------------------------------
// Kernel A: input gates packed into the LSTM's D/C-fragment order (v2):
// float index (((s*8 + w)*64 + lane)*4 + gt), lane = lq*16 + b,
// holds G1[b][s][g = gt*32 + 4w + lq].
// ---------------------------------------------------------------------------
__global__ __launch_bounds__(128) void k_embed_gates(
    const int* __restrict__ x_ids, const float* __restrict__ emb,
    const float* __restrict__ W_ih1, const float* __restrict__ b_ih1,
    const float* __restrict__ b_hh1, float* __restrict__ G1d)
{
    __shared__ float4 xs[4][64];
    const int tid = threadIdx.x;
    const int t0  = blockIdx.x * 4;
    const int r0  = tid >> 6, j = tid & 63;
    #pragma unroll
    for (int rr = 0; rr < 2; ++rr) {
        int r = rr * 2 + r0;
        long id = x_ids[t0 + r];
        xs[r][j] = ((const float4*)(emb + id * (long)D_IN))[j];
    }
    __syncthreads();

    const int g = tid;
    const float4* wrow = (const float4*)(W_ih1 + (long)g * D_IN);
    const float bias = b_ih1[g] + b_hh1[g];
    float a0 = bias, a1 = bias, a2 = bias, a3 = bias;
    #pragma unroll 8
    for (int jj = 0; jj < 64; ++jj) {
        float4 w = wrow[jj];
        a0 += dot4(w, xs[0][jj]);
        a1 += dot4(w, xs[1][jj]);
        a2 += dot4(w, xs[2][jj]);
        a3 += dot4(w, xs[3][jj]);
    }
    const int b  = t0 >> 9;
    const int s0 = t0 & 511;
    const int gt = g >> 5;
    const int u  = g & 31;
    const int w  = u >> 2;
    const int lq = u & 3;
    const int lane = lq * 16 + b;
    float vals[4] = {a0, a1, a2, a3};
    #pragma unroll
    for (int k = 0; k < 4; ++k) {
        G1d[(((long)(s0 + k) * 8 + w) * 64 + lane) * 4 + gt] = vals[k];
    }
}

// ---------------------------------------------------------------------------
// Kernel B: MFMA LSTM v5 = v4 with the h-lo correction dropped from the
// RECURRENCE (6 MFMAs/step, single-precision-bf16 h fragments, half the
// LDS traffic). Stored h2 for the fc passes keeps full hi/lo (flush path
// unchanged, reads f32 ring). Weight hi/lo split retained.
// ---------------------------------------------------------------------------
__global__ __launch_bounds__(512, 1) void k_lstm_mfma(
    const float* __restrict__ G1d,
    const float* __restrict__ W_hh1,
    const float* __restrict__ W_ih2, const float* __restrict__ W_hh2,
    const float* __restrict__ b_ih2, const float* __restrict__ b_hh2,
    bf16* __restrict__ Hhi, bf16* __restrict__ Hlo)
{
    __shared__ alignas(16) bf16 H1h[2][16][40];
    __shared__ alignas(16) bf16 H2h[2][16][40];
    __shared__ alignas(16) float ring[2][16][16][36];   // 72 KB

    const int t  = threadIdx.x;
    const int w  = t >> 6;
    const int l  = t & 63;
    const int lr = l & 15, lq = l >> 4;

    const int garow = (lr & 3) * 32 + 4 * w + (lr >> 2);
    bf16x8 w1h, w1l, wi2h, wi2l, wh2h, wh2l;
    #pragma unroll
    for (int j = 0; j < 8; ++j) {
        float v1 = W_hh1[garow * D_H + lq * 8 + j];
        float v2 = W_ih2[garow * D_H + lq * 8 + j];
        float v3 = W_hh2[garow * D_H + lq * 8 + j];
        bf16 b1 = (bf16)v1, b2 = (bf16)v2, b3 = (bf16)v3;
        w1h[j]  = b1; w1l[j]  = (bf16)(v1 - (float)b1);
        wi2h[j] = b2; wi2l[j] = (bf16)(v2 - (float)b2);
        wh2h[j] = b3; wh2l[j] = (bf16)(v3 - (float)b3);
    }

    const int u = 4 * w + lq;      // this lane's cell unit; batch = lr
    f32x4 bias2;
    #pragma unroll
    for (int r = 0; r < 4; ++r)
        bias2[r] = b_ih2[r * 32 + u] + b_hh2[r * 32 + u];

    bf16x8 h1fh, h2fh;
    #pragma unroll
    for (int j = 0; j < 8; ++j) {
        h1fh[j] = (bf16)0.0f; h2fh[j] = (bf16)0.0f;
    }
    float c1 = 0.0f, c2 = 0.0f;
    const f32x4 z = {0.f, 0.f, 0.f, 0.f};

    const f32x4* G1v = (const f32x4*)G1d;

    // flush chunk cc (steps 16cc..16cc+15) from ring to Hhi/Hlo as hi/lo bf16
    auto flush_chunk = [&](int cc) {
        const int rp   = cc & 1;
        const int pair = t >> 1;
        const int ss   = pair >> 4;
        const int bb   = pair & 15;
        const int u0   = (t & 1) * 16;
        const float* src = &ring[rp][ss][bb][u0];
        const long gbase = ((long)bb * S_LEN + cc * 16 + ss) * D_H + u0;
        #pragma unroll
        for (int q = 0; q < 4; ++q) {
            float4 v = *(const float4*)(src + q * 4);
            bf16 e0 = (bf16)v.x, e1 = (bf16)v.y, e2 = (bf16)v.z, e3 = (bf16)v.w;
            bf16x4 hv = {e0, e1, e2, e3};
            bf16x4 lv = {(bf16)(v.x - (float)e0), (bf16)(v.y - (float)e1),
                         (bf16)(v.z - (float)e2), (bf16)(v.w - (float)e3)};
            *(bf16x4*)(Hhi + gbase + q * 4) = hv;
            *(bf16x4*)(Hlo + gbase + q * 4) = lv;
        }
    };

    // one LSTM step: L1(s) + L2(s-1), 1 barrier, 6 MFMAs
    auto step = [&](int s, f32x4 g1c) {
        // L1(s): 2 independent MFMAs (hi + w-lo)
        f32x4 dA = __builtin_amdgcn_mfma_f32_16x16x32_bf16(w1h, h1fh, g1c, 0, 0, 0);
        f32x4 dB = __builtin_amdgcn_mfma_f32_16x16x32_bf16(w1l, h1fh, z, 0, 0, 0);

        // L2(s-1): two independent 2-deep chains
        f32x4 eA, eB;
        if (s > 0) {
            eA = __builtin_amdgcn_mfma_f32_16x16x32_bf16(wi2h, h1fh, bias2, 0, 0, 0);
            eA = __builtin_amdgcn_mfma_f32_16x16x32_bf16(wh2h, h2fh, eA, 0, 0, 0);
            eB = __builtin_amdgcn_mfma_f32_16x16x32_bf16(wi2l, h1fh, z, 0, 0, 0);
            eB = __builtin_amdgcn_mfma_f32_16x16x32_bf16(wh2l, h2fh, eB, 0, 0, 0);
        }

        f32x4 d = dA + dB;
        {
            float iv = sigf(d[0]), fv = sigf(d[1]);
            float gv = tanhfast(d[2]), ov = sigf(d[3]);
            c1 = fv * c1 + iv * gv;
            float h1 = ov * tanhfast(c1);
            H1h[s & 1][lr][u] = (bf16)h1;
        }

        if (s > 0) {
            f32x4 e = eA + eB;
            float iv = sigf(e[0]), fv = sigf(e[1]);
            float gv = tanhfast(e[2]), ov = sigf(e[3]);
            c2 = fv * c2 + iv * gv;
            float h2 = ov * tanhfast(c2);
            H2h[(s - 1) & 1][lr][u] = (bf16)h2;
            ring[((s - 1) >> 4) & 1][(s - 1) & 15][lr][u] = h2;
        }
        __syncthreads();

        h1fh = *(const bf16x8*)&H1h[s & 1][lr][lq * 8];
        if (s > 0) {
            h2fh = *(const bf16x8*)&H2h[(s - 1) & 1][lr][lq * 8];
        }

        if ((s & 15) == 0 && s > 0) {
            flush_chunk((s >> 4) - 1);
        }
    };

    // ---- chunked G1 staging: 64 chunks of 8 steps, double-buffered ----
    f32x4 bufA[8], bufB[8];
    #pragma unroll
    for (int k = 0; k < 8; ++k)
        bufA[k] = G1v[((long)k * 8 + w) * 64 + l];

    #pragma unroll 1
    for (int c = 0; c < 64; c += 2) {
        {   // even chunk: compute from bufA, prefetch chunk c+1 into bufB
            const int cn = c + 1;
            #pragma unroll
            for (int k = 0; k < 8; ++k)
                bufB[k] = G1v[((long)(cn * 8 + k) * 8 + w) * 64 + l];
            #pragma unroll
            for (int k = 0; k < 8; ++k)
                step(c * 8 + k, bufA[k]);
        }
        {   // odd chunk: compute from bufB, prefetch chunk c+2 into bufA
            const int cn = (c + 2 < 64) ? c + 2 : 0;
            #pragma unroll
            for (int k = 0; k < 8; ++k)
                bufA[k] = G1v[((long)(cn * 8 + k) * 8 + w) * 64 + l];
            #pragma unroll
            for (int k = 0; k < 8; ++k)
                step((c + 1) * 8 + k, bufB[k]);
        }
    }

    // ---- epilogue: L2(S_LEN-1) ----
    {
        f32x4 eA = __builtin_amdgcn_mfma_f32_16x16x32_bf16(wi2h, h1fh, bias2, 0, 0, 0);
        eA = __builtin_amdgcn_mfma_f32_16x16x32_bf16(wh2h, h2fh, eA, 0, 0, 0);
        f32x4 eB = __builtin_amdgcn_mfma_f32_16x16x32_bf16(wi2l, h1fh, z, 0, 0, 0);
        eB = __builtin_amdgcn_mfma_f32_16x16x32_bf16(wh2l, h2fh, eB, 0, 0, 0);
        f32x4 e = eA + eB;
        float iv = sigf(e[0]), fv = sigf(e[1]);
        float gv = tanhfast(e[2]), ov = sigf(e[3]);
        c2 = fv * c2 + iv * gv;
        float h2 = ov * tanhfast(c2);
        ring[((S_LEN - 1) >> 4) & 1][(S_LEN - 1) & 15][lr][u] = h2;
    }
    __syncthreads();
    flush_chunk((S_LEN >> 4) - 1);       // steps 496..511
}

// ---------------------------------------------------------------------------
// Kernel C1 (MFMA): partial softmax denominators.
// ---------------------------------------------------------------------------
__global__ __launch_bounds__(256) void k_fc_sum(
    const bf16* __restrict__ Hhi, const bf16* __restrict__ Hlo,
    const bf16* __restrict__ Whi, const bf16* __restrict__ Wlo,
    const float* __restrict__ b_fc, float* __restrict__ partial)
{
    const int lane = threadIdx.x & 63;
    const int wid  = threadIdx.x >> 6;
    const int tg   = blockIdx.x / NV1;
    const int nv   = blockIdx.x % NV1;
    const int t0   = tg * 128 + wid * 32;
    const int lr   = lane & 15, lq = lane >> 4;

    const long arow0 = (long)(t0 + lr) * D_H + lq * 8;
    const long arow1 = arow0 + 16 * D_H;
    bf16x8 a0h = *(const bf16x8*)(Hhi + arow0);
    bf16x8 a0l = *(const bf16x8*)(Hlo + arow0);
    bf16x8 a1h = *(const bf16x8*)(Hhi + arow1);
    bf16x8 a1l = *(const bf16x8*)(Hlo + arow1);

    f32x4 acc0 = {0.f, 0.f, 0.f, 0.f}, acc1 = {0.f, 0.f, 0.f, 0.f};
    const f32x4 z = {0.f, 0.f, 0.f, 0.f};
    int v0 = nv * (VOCAB / NV1);
    for (int tile = 0; tile < VT1; ++tile, v0 += 16) {
        const long brow = (long)(v0 + lr) * D_H + lq * 8;
        bf16x8 bh = *(const bf16x8*)(Whi + brow);
        bf16x8 bl = *(const bf16x8*)(Wlo + brow);
        float bias = b_fc[v0 + lr];
        f32x4 d0 = __builtin_amdgcn_mfma_f32_16x16x32_bf16(a0h, bh, z, 0, 0, 0);
        d0 = __builtin_amdgcn_mfma_f32_16x16x32_bf16(a0l, bh, d0, 0, 0, 0);
        d0 = __builtin_amdgcn_mfma_f32_16x16x32_bf16(a0h, bl, d0, 0, 0, 0);
        f32x4 d1 = __builtin_amdgcn_mfma_f32_16x16x32_bf16(a1h, bh, z, 0, 0, 0);
        d1 = __builtin_amdgcn_mfma_f32_16x16x32_bf16(a1l, bh, d1, 0, 0, 0);
        d1 = __builtin_amdgcn_mfma_f32_16x16x32_bf16(a1h, bl, d1, 0, 0, 0);
        #pragma unroll
        for (int r = 0; r < 4; ++r) {
            acc0[r] += __expf(d0[r] + bias);
            acc1[r] += __expf(d1[r] + bias);
        }
    }

    #pragma unroll
    for (int m = 1; m < 16; m <<= 1) {
        #pragma unroll
        for (int r = 0; r < 4; ++r) {
            acc0[r] += __shfl_xor(acc0[r], m, 64);
            acc1[r] += __shfl_xor(acc1[r], m, 64);
        }
    }
    if (lr == 0) {
        #pragma unroll
        for (int r = 0; r < 4; ++r) {
            partial[(long)nv * NTOK + t0 + lq * 4 + r]      = acc0[r];
            partial[(long)nv * NTOK + t0 + 16 + lq * 4 + r] = acc1[r];
        }
    }
}

__global__ __launch_bounds__(256) void k_inv(
    const float* __restrict__ partial, float* __restrict__ inv_sum)
{
    const int t = blockIdx.x * 256 + threadIdx.x;
    float s = 0.0f;
    #pragma unroll
    for (int nv = 0; nv < NV1; ++nv) s += partial[(long)nv * NTOK + t];
    inv_sum[t] = 1.0f / s;
}

// ---------------------------------------------------------------------------
// Kernel C2 (MFMA): recompute logits, write normalized softmax.
// ---------------------------------------------------------------------------
__global__ __launch_bounds__(256) void k_fc_out(
    const bf16* __restrict__ Hhi, const bf16* __restrict__ Hlo,
    const bf16* __restrict__ Whi, const bf16* __restrict__ Wlo,
    const float* __restrict__ b_fc, const float* __restrict__ inv_sum,
    float* __restrict__ out)
{
    const int lane = threadIdx.x & 63;
    const int wid  = threadIdx.x >> 6;
    const int tg   = blockIdx.x / NV2;
    const int nv   = blockIdx.x % NV2;
    const int t0   = tg * 128 + wid * 32;
    const int lr   = lane & 15, lq = lane >> 4;

    const long arow0 = (long)(t0 + lr) * D_H + lq * 8;
    const long arow1 = arow0 + 16 * D_H;
    bf16x8 a0h = *(const bf16x8*)(Hhi + arow0);
    bf16x8 a0l = *(const bf16x8*)(Hlo + arow0);
    bf16x8 a1h = *(const bf16x8*)(Hhi + arow1);
    bf16x8 a1l = *(const bf16x8*)(Hlo + arow1);

    float inv0[4], inv1[4];
    #pragma unroll
    for (int r = 0; r < 4; ++r) {
        inv0[r] = inv_sum[t0 + lq * 4 + r];
        inv1[r] = inv_sum[t0 + 16 + lq * 4 + r];
    }

    const f32x4 z = {0.f, 0.f, 0.f, 0.f};
    int v0 = nv * (VOCAB / NV2);
    for (int tile = 0; tile < VT2; ++tile, v0 += 16) {
        const long brow = (long)(v0 + lr) * D_H + lq * 8;
        bf16x8 bh = *(const bf16x8*)(Whi + brow);
        bf16x8 bl = *(const bf16x8*)(Wlo + brow);
        float bias = b_fc[v0 + lr];
        f32x4 d0 = __builtin_amdgcn_mfma_f32_16x16x32_bf16(a0h, bh, z, 0, 0, 0);
        d0 = __builtin_amdgcn_mfma_f32_16x16x32_bf16(a0l, bh, d0, 0, 0, 0);
        d0 = __builtin_amdgcn_mfma_f32_16x16x32_bf16(a0h, bl, d0, 0, 0, 0);
        f32x4 d1 = __builtin_amdgcn_mfma_f32_16x16x32_bf16(a1h, bh, z, 0, 0, 0);
        d1 = __builtin_amdgcn_mfma_f32_16x16x32_bf16(a1l, bh, d1, 0, 0, 0);
        d1 = __builtin_amdgcn_mfma_f32_16x16x32_bf16(a1h, bl, d1, 0, 0, 0);
        const int vcol = v0 + lr;
        #pragma unroll
        for (int r = 0; r < 4; ++r) {
            out[(long)(t0 + lq * 4 + r) * VOCAB + vcol] =
                __expf(d0[r] + bias) * inv0[r];
            out[(long)(t0 + 16 + lq * 4 + r) * VOCAB + vcol] =
                __expf(d1[r] + bias) * inv1[r];
        }
    }
}

// ---------------------------------------------------------------------------
extern "C" void kernel_launch(void* const* d_in, const int* in_sizes, int n_in,
                              void* d_out, int out_size, void* d_ws, size_t ws_size,
                              hipStream_t stream)
{
    const int*   x_ids = (const int*)d_in[0];
    const float* emb   = (const float*)d_in[1];
    const float* W_ih1 = (const float*)d_in[2];
    const float* W_hh1 = (const float*)d_in[3];
    const float* b_ih1 = (const float*)d_in[4];
    const float* b_hh1 = (const float*)d_in[5];
    const float* W_ih2 = (const float*)d_in[6];
    const float* W_hh2 = (const float*)d_in[7];
    const float* b_ih2 = (const float*)d_in[8];
    const float* b_hh2 = (const float*)d_in[9];
    const float* W_fc  = (const float*)d_in[10];
    const float* b_fc  = (const float*)d_in[11];
    float* out = (float*)d_out;

    char* p = (char*)d_ws;
    float* G1d     = (float*)p;            p += (long)S_LEN * 8 * 64 * 4 * 4; // 4 MB
    bf16* Hhi      = (bf16*)p;             p += (long)NTOK * D_H * 2;   // 512 KB
    bf16* Hlo      = (bf16*)p;             p += (long)NTOK * D_H * 2;   // 512 KB
    bf16* Whi      = (bf16*)p;             p += (long)VOCAB * D_H * 2;  // 2 MB
    bf16* Wlo      = (bf16*)p;             p += (long)VOCAB * D_H * 2;  // 2 MB
    float* partial = (float*)p;            p += (long)NV1 * NTOK * 4;   // 512 KB
    float* inv_sum = (float*)p;            p += (long)NTOK * 4;         // 32 KB

    k_cvt_w<<<VOCAB * D_H / (256 * 4), 256, 0, stream>>>(W_fc, Whi, Wlo);
    k_embed_gates<<<NTOK / 4, 128, 0, stream>>>(x_ids, emb, W_ih1, b_ih1, b_hh1, G1d);
    k_lstm_mfma<<<1, 512, 0, stream>>>(G1d, W_hh1, W_ih2, W_hh2, b_ih2, b_hh2, Hhi, Hlo);
    k_fc_sum<<<(NTOK / 128) * NV1, 256, 0, stream>>>(Hhi, Hlo, Whi, Wlo, b_fc, partial);
    k_inv<<<NTOK / 256, 256, 0, stream>>>(partial, inv_sum);
    k_fc_out<<<(NTOK / 128) * NV2, 256, 0, stream>>>(Hhi, Hlo, Whi, Wlo, b_fc, inv_sum, out);
}

// Round 19
// 636.715 us; speedup vs baseline: 10.9206x; 1.0241x over previous
//
#include <hip/hip_runtime.h>
#include <math.h>

#define VOCAB 32000
#define D_IN  256
#define D_H   32
#define B_SZ  16
#define S_LEN 512
#define NTOK  (B_SZ * S_LEN)   // 8192
#define NV1   25               // vocab splits in sum pass
#define VT1   (VOCAB / 16 / NV1)   // 80 tiles of 16 rows
#define NV2   25               // vocab splits in out pass
#define VT2   (VOCAB / 16 / NV2)   // 80 tiles

typedef __bf16 bf16;
typedef __attribute__((ext_vector_type(8))) __bf16 bf16x8;
typedef __attribute__((ext_vector_type(4))) __bf16 bf16x4;
typedef __attribute__((ext_vector_type(4))) float f32x4;

__device__ __forceinline__ float rcpf(float x) {
    return __builtin_amdgcn_rcpf(x);
}

__device__ __forceinline__ float sigf(float x) {
    return rcpf(1.0f + __expf(-x));
}

__device__ __forceinline__ float tanhfast(float x) {
    float ax = fabsf(x);
    float e = __expf(-2.0f * ax);
    float r = (1.0f - e) * rcpf(1.0f + e);
    return copysignf(r, x);
}

__device__ __forceinline__ float dot4(float4 a, float4 b) {
    return a.x * b.x + a.y * b.y + a.z * b.z + a.w * b.w;
}

// ---------------------------------------------------------------------------
// Convert W_fc (f32 [32000][32]) to bf16 hi/lo split arrays.
// ---------------------------------------------------------------------------
__global__ __launch_bounds__(256) void k_cvt_w(
    const float* __restrict__ W, bf16* __restrict__ Whi, bf16* __restrict__ Wlo)
{
    const long i = ((long)blockIdx.x * 256 + threadIdx.x) * 4;
    float4 w = *(const float4*)(W + i);
    bf16 h0 = (bf16)w.x, h1 = (bf16)w.y, h2 = (bf16)w.z, h3 = (bf16)w.w;
    bf16 l0 = (bf16)(w.x - (float)h0), l1 = (bf16)(w.y - (float)h1);
    bf16 l2 = (bf16)(w.z - (float)h2), l3 = (bf16)(w.w - (float)h3);
    bf16x4 hv = {h0, h1, h2, h3}, lv = {l0, l1, l2, l3};
    *(bf16x4*)(Whi + i) = hv;
    *(bf16x4*)(Wlo + i) = lv;
}

// ---------------------------------------------------------------------------
// Kernel A: input gates packed into the LSTM's D/C-fragment order (v2):
// float index (((s*8 + w)*64 + lane)*4 + gt), lane = lq*16 + b,
// holds G1[b][s][g = gt*32 + 4w + lq].
// ---------------------------------------------------------------------------
__global__ __launch_bounds__(128) void k_embed_gates(
    const int* __restrict__ x_ids, const float* __restrict__ emb,
    const float* __restrict__ W_ih1, const float* __restrict__ b_ih1,
    const float* __restrict__ b_hh1, float* __restrict__ G1d)
{
    __shared__ float4 xs[4][64];
    const int tid = threadIdx.x;
    const int t0  = blockIdx.x * 4;
    const int r0  = tid >> 6, j = tid & 63;
    #pragma unroll
    for (int rr = 0; rr < 2; ++rr) {
        int r = rr * 2 + r0;
        long id = x_ids[t0 + r];
        xs[r][j] = ((const float4*)(emb + id * (long)D_IN))[j];
    }
    __syncthreads();

    const int g = tid;
    const float4* wrow = (const float4*)(W_ih1 + (long)g * D_IN);
    const float bias = b_ih1[g] + b_hh1[g];
    float a0 = bias, a1 = bias, a2 = bias, a3 = bias;
    #pragma unroll 8
    for (int jj = 0; jj < 64; ++jj) {
        float4 w = wrow[jj];
        a0 += dot4(w, xs[0][jj]);
        a1 += dot4(w, xs[1][jj]);
        a2 += dot4(w, xs[2][jj]);
        a3 += dot4(w, xs[3][jj]);
    }
    const int b  = t0 >> 9;
    const int s0 = t0 & 511;
    const int gt = g >> 5;
    const int u  = g & 31;
    const int w  = u >> 2;
    const int lq = u & 3;
    const int lane = lq * 16 + b;
    float vals[4] = {a0, a1, a2, a3};
    #pragma unroll
    for (int k = 0; k < 4; ++k) {
        G1d[(((long)(s0 + k) * 8 + w) * 64 + lane) * 4 + gt] = vals[k];
    }
}

// ---------------------------------------------------------------------------
// Kernel B: MFMA LSTM v6 = v5 with the WEIGHT-lo correction also dropped
// from the recurrence: 3 MFMAs/step (L1: 1, L2: 2-deep chain), pure-bf16
// weights + h in the recurrence. Stored h2 for the fc passes keeps full
// hi/lo precision (flush reads the f32 ring - unchanged).
// ---------------------------------------------------------------------------
__global__ __launch_bounds__(512, 1) void k_lstm_mfma(
    const float* __restrict__ G1d,
    const float* __restrict__ W_hh1,
    const float* __restrict__ W_ih2, const float* __restrict__ W_hh2,
    const float* __restrict__ b_ih2, const float* __restrict__ b_hh2,
    bf16* __restrict__ Hhi, bf16* __restrict__ Hlo)
{
    __shared__ alignas(16) bf16 H1h[2][16][40];
    __shared__ alignas(16) bf16 H2h[2][16][40];
    __shared__ alignas(16) float ring[2][16][16][36];   // 72 KB

    const int t  = threadIdx.x;
    const int w  = t >> 6;
    const int l  = t & 63;
    const int lr = l & 15, lq = l >> 4;

    const int garow = (lr & 3) * 32 + 4 * w + (lr >> 2);
    bf16x8 w1h, wi2h, wh2h;
    #pragma unroll
    for (int j = 0; j < 8; ++j) {
        w1h[j]  = (bf16)W_hh1[garow * D_H + lq * 8 + j];
        wi2h[j] = (bf16)W_ih2[garow * D_H + lq * 8 + j];
        wh2h[j] = (bf16)W_hh2[garow * D_H + lq * 8 + j];
    }

    const int u = 4 * w + lq;      // this lane's cell unit; batch = lr
    f32x4 bias2;
    #pragma unroll
    for (int r = 0; r < 4; ++r)
        bias2[r] = b_ih2[r * 32 + u] + b_hh2[r * 32 + u];

    bf16x8 h1fh, h2fh;
    #pragma unroll
    for (int j = 0; j < 8; ++j) {
        h1fh[j] = (bf16)0.0f; h2fh[j] = (bf16)0.0f;
    }
    float c1 = 0.0f, c2 = 0.0f;

    const f32x4* G1v = (const f32x4*)G1d;

    // flush chunk cc (steps 16cc..16cc+15) from ring to Hhi/Hlo as hi/lo bf16
    auto flush_chunk = [&](int cc) {
        const int rp   = cc & 1;
        const int pair = t >> 1;
        const int ss   = pair >> 4;
        const int bb   = pair & 15;
        const int u0   = (t & 1) * 16;
        const float* src = &ring[rp][ss][bb][u0];
        const long gbase = ((long)bb * S_LEN + cc * 16 + ss) * D_H + u0;
        #pragma unroll
        for (int q = 0; q < 4; ++q) {
            float4 v = *(const float4*)(src + q * 4);
            bf16 e0 = (bf16)v.x, e1 = (bf16)v.y, e2 = (bf16)v.z, e3 = (bf16)v.w;
            bf16x4 hv = {e0, e1, e2, e3};
            bf16x4 lv = {(bf16)(v.x - (float)e0), (bf16)(v.y - (float)e1),
                         (bf16)(v.z - (float)e2), (bf16)(v.w - (float)e3)};
            *(bf16x4*)(Hhi + gbase + q * 4) = hv;
            *(bf16x4*)(Hlo + gbase + q * 4) = lv;
        }
    };

    // one LSTM step: L1(s) + L2(s-1), 1 barrier, 3 MFMAs
    auto step = [&](int s, f32x4 g1c) {
        // L1(s): single MFMA
        f32x4 d = __builtin_amdgcn_mfma_f32_16x16x32_bf16(w1h, h1fh, g1c, 0, 0, 0);

        // L2(s-1): one 2-deep chain
        f32x4 e;
        if (s > 0) {
            e = __builtin_amdgcn_mfma_f32_16x16x32_bf16(wi2h, h1fh, bias2, 0, 0, 0);
            e = __builtin_amdgcn_mfma_f32_16x16x32_bf16(wh2h, h2fh, e, 0, 0, 0);
        }

        {
            float iv = sigf(d[0]), fv = sigf(d[1]);
            float gv = tanhfast(d[2]), ov = sigf(d[3]);
            c1 = fv * c1 + iv * gv;
            float h1 = ov * tanhfast(c1);
            H1h[s & 1][lr][u] = (bf16)h1;
        }

        if (s > 0) {
            float iv = sigf(e[0]), fv = sigf(e[1]);
            float gv = tanhfast(e[2]), ov = sigf(e[3]);
            c2 = fv * c2 + iv * gv;
            float h2 = ov * tanhfast(c2);
            H2h[(s - 1) & 1][lr][u] = (bf16)h2;
            ring[((s - 1) >> 4) & 1][(s - 1) & 15][lr][u] = h2;
        }
        __syncthreads();

        h1fh = *(const bf16x8*)&H1h[s & 1][lr][lq * 8];
        if (s > 0) {
            h2fh = *(const bf16x8*)&H2h[(s - 1) & 1][lr][lq * 8];
        }

        if ((s & 15) == 0 && s > 0) {
            flush_chunk((s >> 4) - 1);
        }
    };

    // ---- chunked G1 staging: 64 chunks of 8 steps, double-buffered ----
    f32x4 bufA[8], bufB[8];
    #pragma unroll
    for (int k = 0; k < 8; ++k)
        bufA[k] = G1v[((long)k * 8 + w) * 64 + l];

    #pragma unroll 1
    for (int c = 0; c < 64; c += 2) {
        {   // even chunk: compute from bufA, prefetch chunk c+1 into bufB
            const int cn = c + 1;
            #pragma unroll
            for (int k = 0; k < 8; ++k)
                bufB[k] = G1v[((long)(cn * 8 + k) * 8 + w) * 64 + l];
            #pragma unroll
            for (int k = 0; k < 8; ++k)
                step(c * 8 + k, bufA[k]);
        }
        {   // odd chunk: compute from bufB, prefetch chunk c+2 into bufA
            const int cn = (c + 2 < 64) ? c + 2 : 0;
            #pragma unroll
            for (int k = 0; k < 8; ++k)
                bufA[k] = G1v[((long)(cn * 8 + k) * 8 + w) * 64 + l];
            #pragma unroll
            for (int k = 0; k < 8; ++k)
                step((c + 1) * 8 + k, bufB[k]);
        }
    }

    // ---- epilogue: L2(S_LEN-1) ----
    {
        f32x4 e = __builtin_amdgcn_mfma_f32_16x16x32_bf16(wi2h, h1fh, bias2, 0, 0, 0);
        e = __builtin_amdgcn_mfma_f32_16x16x32_bf16(wh2h, h2fh, e, 0, 0, 0);
        float iv = sigf(e[0]), fv = sigf(e[1]);
        float gv = tanhfast(e[2]), ov = sigf(e[3]);
        c2 = fv * c2 + iv * gv;
        float h2 = ov * tanhfast(c2);
        ring[((S_LEN - 1) >> 4) & 1][(S_LEN - 1) & 15][lr][u] = h2;
    }
    __syncthreads();
    flush_chunk((S_LEN >> 4) - 1);       // steps 496..511
}

// ---------------------------------------------------------------------------
// Kernel C1 (MFMA): partial softmax denominators.
// ---------------------------------------------------------------------------
__global__ __launch_bounds__(256) void k_fc_sum(
    const bf16* __restrict__ Hhi, const bf16* __restrict__ Hlo,
    const bf16* __restrict__ Whi, const bf16* __restrict__ Wlo,
    const float* __restrict__ b_fc, float* __restrict__ partial)
{
    const int lane = threadIdx.x & 63;
    const int wid  = threadIdx.x >> 6;
    const int tg   = blockIdx.x / NV1;
    const int nv   = blockIdx.x % NV1;
    const int t0   = tg * 128 + wid * 32;
    const int lr   = lane & 15, lq = lane >> 4;

    const long arow0 = (long)(t0 + lr) * D_H + lq * 8;
    const long arow1 = arow0 + 16 * D_H;
    bf16x8 a0h = *(const bf16x8*)(Hhi + arow0);
    bf16x8 a0l = *(const bf16x8*)(Hlo + arow0);
    bf16x8 a1h = *(const bf16x8*)(Hhi + arow1);
    bf16x8 a1l = *(const bf16x8*)(Hlo + arow1);

    f32x4 acc0 = {0.f, 0.f, 0.f, 0.f}, acc1 = {0.f, 0.f, 0.f, 0.f};
    const f32x4 z = {0.f, 0.f, 0.f, 0.f};
    int v0 = nv * (VOCAB / NV1);
    for (int tile = 0; tile < VT1; ++tile, v0 += 16) {
        const long brow = (long)(v0 + lr) * D_H + lq * 8;
        bf16x8 bh = *(const bf16x8*)(Whi + brow);
        bf16x8 bl = *(const bf16x8*)(Wlo + brow);
        float bias = b_fc[v0 + lr];
        f32x4 d0 = __builtin_amdgcn_mfma_f32_16x16x32_bf16(a0h, bh, z, 0, 0, 0);
        d0 = __builtin_amdgcn_mfma_f32_16x16x32_bf16(a0l, bh, d0, 0, 0, 0);
        d0 = __builtin_amdgcn_mfma_f32_16x16x32_bf16(a0h, bl, d0, 0, 0, 0);
        f32x4 d1 = __builtin_amdgcn_mfma_f32_16x16x32_bf16(a1h, bh, z, 0, 0, 0);
        d1 = __builtin_amdgcn_mfma_f32_16x16x32_bf16(a1l, bh, d1, 0, 0, 0);
        d1 = __builtin_amdgcn_mfma_f32_16x16x32_bf16(a1h, bl, d1, 0, 0, 0);
        #pragma unroll
        for (int r = 0; r < 4; ++r) {
            acc0[r] += __expf(d0[r] + bias);
            acc1[r] += __expf(d1[r] + bias);
        }
    }

    #pragma unroll
    for (int m = 1; m < 16; m <<= 1) {
        #pragma unroll
        for (int r = 0; r < 4; ++r) {
            acc0[r] += __shfl_xor(acc0[r], m, 64);
            acc1[r] += __shfl_xor(acc1[r], m, 64);
        }
    }
    if (lr == 0) {
        #pragma unroll
        for (int r = 0; r < 4; ++r) {
            partial[(long)nv * NTOK + t0 + lq * 4 + r]      = acc0[r];
            partial[(long)nv * NTOK + t0 + 16 + lq * 4 + r] = acc1[r];
        }
    }
}

__global__ __launch_bounds__(256) void k_inv(
    const float* __restrict__ partial, float* __restrict__ inv_sum)
{
    const int t = blockIdx.x * 256 + threadIdx.x;
    float s = 0.0f;
    #pragma unroll
    for (int nv = 0; nv < NV1; ++nv) s += partial[(long)nv * NTOK + t];
    inv_sum[t] = 1.0f / s;
}

// ---------------------------------------------------------------------------
// Kernel C2 (MFMA): recompute logits, write normalized softmax.
// ---------------------------------------------------------------------------
__global__ __launch_bounds__(256) void k_fc_out(
    const bf16* __restrict__ Hhi, const bf16* __restrict__ Hlo,
    const bf16* __restrict__ Whi, const bf16* __restrict__ Wlo,
    const float* __restrict__ b_fc, const float* __restrict__ inv_sum,
    float* __restrict__ out)
{
    const int lane = threadIdx.x & 63;
    const int wid  = threadIdx.x >> 6;
    const int tg   = blockIdx.x / NV2;
    const int nv   = blockIdx.x % NV2;
    const int t0   = tg * 128 + wid * 32;
    const int lr   = lane & 15, lq = lane >> 4;

    const long arow0 = (long)(t0 + lr) * D_H + lq * 8;
    const long arow1 = arow0 + 16 * D_H;
    bf16x8 a0h = *(const bf16x8*)(Hhi + arow0);
    bf16x8 a0l = *(const bf16x8*)(Hlo + arow0);
    bf16x8 a1h = *(const bf16x8*)(Hhi + arow1);
    bf16x8 a1l = *(const bf16x8*)(Hlo + arow1);

    float inv0[4], inv1[4];
    #pragma unroll
    for (int r = 0; r < 4; ++r) {
        inv0[r] = inv_sum[t0 + lq * 4 + r];
        inv1[r] = inv_sum[t0 + 16 + lq * 4 + r];
    }

    const f32x4 z = {0.f, 0.f, 0.f, 0.f};
    int v0 = nv * (VOCAB / NV2);
    for (int tile = 0; tile < VT2; ++tile, v0 += 16) {
        const long brow = (long)(v0 + lr) * D_H + lq * 8;
        bf16x8 bh = *(const bf16x8*)(Whi + brow);
        bf16x8 bl = *(const bf16x8*)(Wlo + brow);
        float bias = b_fc[v0 + lr];
        f32x4 d0 = __builtin_amdgcn_mfma_f32_16x16x32_bf16(a0h, bh, z, 0, 0, 0);
        d0 = __builtin_amdgcn_mfma_f32_16x16x32_bf16(a0l, bh, d0, 0, 0, 0);
        d0 = __builtin_amdgcn_mfma_f32_16x16x32_bf16(a0h, bl, d0, 0, 0, 0);
        f32x4 d1 = __builtin_amdgcn_mfma_f32_16x16x32_bf16(a1h, bh, z, 0, 0, 0);
        d1 = __builtin_amdgcn_mfma_f32_16x16x32_bf16(a1l, bh, d1, 0, 0, 0);
        d1 = __builtin_amdgcn_mfma_f32_16x16x32_bf16(a1h, bl, d1, 0, 0, 0);
        const int vcol = v0 + lr;
        #pragma unroll
        for (int r = 0; r < 4; ++r) {
            out[(long)(t0 + lq * 4 + r) * VOCAB + vcol] =
                __expf(d0[r] + bias) * inv0[r];
            out[(long)(t0 + 16 + lq * 4 + r) * VOCAB + vcol] =
                __expf(d1[r] + bias) * inv1[r];
        }
    }
}

// ---------------------------------------------------------------------------
extern "C" void kernel_launch(void* const* d_in, const int* in_sizes, int n_in,
                              void* d_out, int out_size, void* d_ws, size_t ws_size,
                              hipStream_t stream)
{
    const int*   x_ids = (const int*)d_in[0];
    const float* emb   = (const float*)d_in[1];
    const float* W_ih1 = (const float*)d_in[2];
    const float* W_hh1 = (const float*)d_in[3];
    const float* b_ih1 = (const float*)d_in[4];
    const float* b_hh1 = (const float*)d_in[5];
    const float* W_ih2 = (const float*)d_in[6];
    const float* W_hh2 = (const float*)d_in[7];
    const float* b_ih2 = (const float*)d_in[8];
    const float* b_hh2 = (const float*)d_in[9];
    const float* W_fc  = (const float*)d_in[10];
    const float* b_fc  = (const float*)d_in[11];
    float* out = (float*)d_out;

    char* p = (char*)d_ws;
    float* G1d     = (float*)p;            p += (long)S_LEN * 8 * 64 * 4 * 4; // 4 MB
    bf16* Hhi      = (bf16*)p;             p += (long)NTOK * D_H * 2;   // 512 KB
    bf16* Hlo      = (bf16*)p;             p += (long)NTOK * D_H * 2;   // 512 KB
    bf16* Whi      = (bf16*)p;             p += (long)VOCAB * D_H * 2;  // 2 MB
    bf16* Wlo      = (bf16*)p;             p += (long)VOCAB * D_H * 2;  // 2 MB
    float* partial = (float*)p;            p += (long)NV1 * NTOK * 4;   // 800 KB
    float* inv_sum = (float*)p;            p += (long)NTOK * 4;         // 32 KB

    k_cvt_w<<<VOCAB * D_H / (256 * 4), 256, 0, stream>>>(W_fc, Whi, Wlo);
    k_embed_gates<<<NTOK / 4, 128, 0, stream>>>(x_ids, emb, W_ih1, b_ih1, b_hh1, G1d);
    k_lstm_mfma<<<1, 512, 0, stream>>>(G1d, W_hh1, W_ih2, W_hh2, b_ih2, b_hh2, Hhi, Hlo);
    k_fc_sum<<<(NTOK / 128) * NV1, 256, 0, stream>>>(Hhi, Hlo, Whi, Wlo, b_fc, partial);
    k_inv<<<NTOK / 256, 256, 0, stream>>>(partial, inv_sum);
    k_fc_out<<<(NTOK / 128) * NV2, 256, 0, stream>>>(Hhi, Hlo, Whi, Wlo, b_fc, inv_sum, out);
}